// Round 14
// baseline (1253.993 us; speedup 1.0000x reference)
//
#include <hip/hip_runtime.h>
#include <hip/hip_bf16.h>

// Round 14: halve sync frequency. Cores now use a 64KB-granularity double buffer
// (buffer = {A0,B0,A1,B1} = 4x16KB; LDS 128KB, same 1 block/CU as 96KB ring-3).
// Per K=64 mega-step: 24 ds_read_b128 + 8 gl_lds (stage next tile -> other buf)
// + 64 MFMA + ONE vmcnt(0) + ONE barrier (was 2 of each per K=64).
// WAR: staged buffer's readers completed last mega-step pre-barrier (lgkm forced
// by their MFMAs). RAW: per-wave vmcnt(0) over own loads + barrier; drain cover
// = full mega-step (~2400cyc) >> 900cyc HBM-miss. Tiers/packs/convs = round 13.

#define HDIM 4096
#define IDIM 11008
#define N2   22016
#define MTOK 2048
#define KT1  64      // HDIM/64
#define KT2  172     // IDIM/64
#define NB1  86      // IDIM/128
#define NB2  32      // HDIM/128

// per-expert pack strides in SHORTS (tile = 16384 shorts = 32 KB)
#define XPE_SH ((long)8 * KT1 * 16384)    //  16.8 MB
#define WPE_SH ((long)NB1 * KT1 * 16384)  // 180.4 MB
#define HPE_SH ((long)8 * KT2 * 16384)    //  45.1 MB

typedef unsigned short ushort_t;
using f32x4  = __attribute__((ext_vector_type(4))) float;
using bf16x8 = __attribute__((ext_vector_type(8))) short;
using u32x2  = __attribute__((ext_vector_type(2))) unsigned int;
using u32x4  = __attribute__((ext_vector_type(4))) unsigned int;

__device__ __forceinline__ unsigned int bf16rne(float f) {
    unsigned int u = __builtin_bit_cast(unsigned int, f);
    return (u + 0x7FFFu + ((u >> 16) & 1u)) >> 16;
}
__device__ __forceinline__ unsigned int pack2(float lo, float hi) {
    return bf16rne(lo) | (bf16rne(hi) << 16);
}
__device__ __forceinline__ void gl_lds16(const void* g, void* l) {
    __builtin_amdgcn_global_load_lds(
        (const __attribute__((address_space(1))) void*)g,
        (__attribute__((address_space(3))) void*)l, 16, 0, 0);
}

// ---------------- conversion kernels (fp32 -> packed bf16 units, proven) ----------------

__global__ __launch_bounds__(256)
void conv_x(const float* __restrict__ X, ushort_t* __restrict__ XP) {
    int bid = blockIdx.x;               // 16 mb128 * 64 kt
    int mb = bid >> 6, kt = bid & 63;
    int t = threadIdx.x;
    int r0 = t >> 4, c4 = t & 15;
    int kh = c4 >> 3, c = (c4 >> 1) & 3, lo4 = (c4 & 1) << 2;
    ushort_t* tp = XP + ((long)(mb >> 1) * KT1 + kt) * 16384 + (long)kh * 8192 + (mb & 1) * 4096;
#pragma unroll
    for (int p = 0; p < 8; ++p) {
        int rl = r0 + p * 16;
        f32x4 v = *(const f32x4*)(X + (long)(mb * 128 + rl) * HDIM + kt * 64 + c4 * 4);
        u32x2 pk = { pack2(v[0], v[1]), pack2(v[2], v[3]) };
        int q = rl >> 1;
        int pos = ((((rl & 1) << 2) | c) ^ (q & 7));
        *(u32x2*)&tp[q * 64 + pos * 8 + lo4] = pk;
    }
}

__global__ __launch_bounds__(256)
void conv_wgu(const float* __restrict__ W, ushort_t* __restrict__ WP) {
    int bid = blockIdx.x;               // nb(86)*kt(64)*e(2)
    int e = bid & 1, kt = (bid >> 1) & 63, nb = bid >> 7;
    int t = threadIdx.x;
    int kp = t >> 5, c4 = t & 31;
    const float* p = W + ((long)kt * 64 + kp * 8) * N2 + (long)e * IDIM + nb * 128 + c4 * 4;
    f32x4 v[8];
#pragma unroll
    for (int j = 0; j < 8; ++j) v[j] = *(const f32x4*)(p + (long)j * N2);
    ushort_t* tp = WP + ((long)nb * KT1 + kt) * 16384 + (long)(kp >> 2) * 8192 + e * 4096;
    int c = kp & 3;
#pragma unroll
    for (int cc = 0; cc < 4; ++cc) {
        int n = c4 * 4 + cc;
        int q = n >> 1;
        int pos = ((((n & 1) << 2) | c) ^ (q & 7));
        u32x4 pk = { pack2(v[0][cc], v[1][cc]), pack2(v[2][cc], v[3][cc]),
                     pack2(v[4][cc], v[5][cc]), pack2(v[6][cc], v[7][cc]) };
        *(u32x4*)&tp[q * 64 + pos * 8] = pk;
    }
}

__global__ __launch_bounds__(256)
void conv_wd2b(const float* __restrict__ Wl, const float* __restrict__ Wv,
               ushort_t* __restrict__ WPd) {
    int bid = blockIdx.x;               // 32*KT2
    int kt = bid % KT2, nbp = bid / KT2;
    int e = nbp >> 4, nb = nbp & 15;
    const float* W = e ? Wv : Wl;
    int t = threadIdx.x;
    int kp = t >> 5, c4 = t & 31;
    ushort_t* tp = WPd + ((long)nbp * KT2 + kt) * 16384 + (long)(kp >> 2) * 8192;
    int c = kp & 3;
#pragma unroll
    for (int h = 0; h < 2; ++h) {
        const float* p = W + ((long)kt * 64 + kp * 8) * HDIM + nb * 256 + h * 128 + c4 * 4;
        f32x4 v[8];
#pragma unroll
        for (int j = 0; j < 8; ++j) v[j] = *(const f32x4*)(p + (long)j * HDIM);
#pragma unroll
        for (int cc = 0; cc < 4; ++cc) {
            int n = h * 128 + c4 * 4 + cc;
            int q = n >> 1;
            int pos = ((((n & 1) << 2) | c) ^ (q & 7));
            u32x4 pk = { pack2(v[0][cc], v[1][cc]), pack2(v[2][cc], v[3][cc]),
                         pack2(v[4][cc], v[5][cc]), pack2(v[6][cc], v[7][cc]) };
            *(u32x4*)&tp[q * 64 + pos * 8] = pk;
        }
    }
}

__global__ __launch_bounds__(256)
void conv_wd(const float* __restrict__ W, ushort_t* __restrict__ WP) {
    int bid = blockIdx.x;               // nb(32)*kt(172)
    int kt = bid % KT2, nb = bid / KT2;
    int t = threadIdx.x;
    int kp = t >> 5, c4 = t & 31;
    const float* p = W + ((long)kt * 64 + kp * 8) * HDIM + nb * 128 + c4 * 4;
    f32x4 v[8];
#pragma unroll
    for (int j = 0; j < 8; ++j) v[j] = *(const f32x4*)(p + (long)j * HDIM);
    ushort_t* tp = WP + ((long)nb * KT2 + kt) * 8192 + (long)(kp >> 2) * 4096;
    int c = kp & 3;
#pragma unroll
    for (int cc = 0; cc < 4; ++cc) {
        int n = c4 * 4 + cc;
        int q = n >> 1;
        int pos = ((((n & 1) << 2) | c) ^ (q & 7));
        u32x4 pk = { pack2(v[0][cc], v[1][cc]), pack2(v[2][cc], v[3][cc]),
                     pack2(v[4][cc], v[5][cc]), pack2(v[6][cc], v[7][cc]) };
        *(u32x4*)&tp[q * 64 + pos * 8] = pk;
    }
}

// stage one 16KB unit (8192 shorts): 2 x global_load_lds per thread, linear dest
#define STAGE_U(SRC, DSTOFF) do { \
    gl_lds16((SRC) + so + lane * 8, &lds[(DSTOFF) + so]); \
    gl_lds16((SRC) + 4096 + so + lane * 8, &lds[(DSTOFF) + 4096 + so]); } while (0)

// stage a full K=64 tile (A + B, 4 units) into buffer at PB
#define STAGE_TILE(NA, NB, PB) do { \
    STAGE_U((NA), (PB)); \
    STAGE_U((NB), (PB) + 8192); \
    STAGE_U((NA) + 8192, (PB) + 16384); \
    STAGE_U((NB) + 8192, (PB) + 24576); } while (0)

#define MFMA16(ACC, AF, BF) \
    _Pragma("unroll") \
    for (int mf = 0; mf < 4; ++mf) \
        _Pragma("unroll") \
        for (int nf = 0; nf < 4; ++nf) \
            ACC[mf][nf] = __builtin_amdgcn_mfma_f32_16x16x32_bf16(AF[mf], BF[nf], ACC[mf][nf], 0, 0, 0);

#define VMCNT_MID(N) do { \
    if (pf) asm volatile("s_waitcnt vmcnt(" #N ")" ::: "memory"); \
    else    asm volatile("s_waitcnt vmcnt(0)" ::: "memory"); } while (0)
#define VMCNT_END(N) do { \
    if (pf) asm volatile("s_waitcnt vmcnt(" #N ")" ::: "memory"); } while (0)

// ---------------- GEMM1: gate/up + silu, 128KB dbuf, ONE barrier per K=64 ----------------
__global__ __launch_bounds__(512, 2)
void gu16_kernel(const ushort_t* __restrict__ XP, const ushort_t* __restrict__ WP,
                 ushort_t* __restrict__ HP, int perE) {
    __shared__ ushort_t lds[65536];     // 2 buf x {A0|B0(g,u)|A1|B1(g,u)} (32KB each)
    int nwg = gridDim.x;                // 688 or 1376 (both %8==0)
    int cpx = nwg >> 3;
    int sw  = (blockIdx.x & 7) * cpx + (blockIdx.x >> 3);
    int e   = (sw >= perE) ? 1 : 0;
    int lsw = sw - e * perE;
    int mblk = lsw & 7;                 // 0..7
    int nblk = lsw >> 3;                // 0..85
    const int t = threadIdx.x, lane = t & 63, w = t >> 6;
    const int wr = w >> 1, wc = w & 1;  // 4M x 2N waves
    const int rr = lane & 15, g4 = lane >> 4;
    const int so = w * 512;

    int aoff[4], boff[4];
#pragma unroll
    for (int mf = 0; mf < 4; ++mf) {
        int m = wr * 64 + mf * 16 + rr, q = m >> 1;
        aoff[mf] = q * 64 + ((((((m & 1) << 2) | g4) ^ (q & 7))) << 3);
    }
#pragma unroll
    for (int nf = 0; nf < 4; ++nf) {
        int n = wc * 64 + nf * 16 + rr, q = n >> 1;
        boff[nf] = q * 64 + ((((((n & 1) << 2) | g4) ^ (q & 7))) << 3);
    }

    f32x4 accg[4][4] = {}, accu[4][4] = {};
    const ushort_t* srcA = XP + (long)e * XPE_SH + (long)mblk * KT1 * 16384;
    const ushort_t* srcB = WP + (long)e * WPE_SH + (long)nblk * KT1 * 16384;
    ushort_t* HPe = HP + (long)e * HPE_SH;

    // prologue: tile 0 -> buf0
    STAGE_TILE(srcA, srcB, 0);
    asm volatile("s_waitcnt vmcnt(0)" ::: "memory");
    __builtin_amdgcn_s_barrier();

    for (int tt = 0; tt < KT1; ++tt) {
        const int cb = (tt & 1) << 15;  // 0 / 32768
        const int pb = cb ^ 32768;
        bf16x8 af[4], bg[4], bu[4];

        // ---- sub-step ks0: units A0/B0 ----
#pragma unroll
        for (int mf = 0; mf < 4; ++mf) af[mf] = *(const bf16x8*)&lds[cb + aoff[mf]];
#pragma unroll
        for (int nf = 0; nf < 4; ++nf) {
            bg[nf] = *(const bf16x8*)&lds[cb + 8192 + boff[nf]];
            bu[nf] = *(const bf16x8*)&lds[cb + 8192 + 4096 + boff[nf]];
        }
        if (tt + 1 < KT1) {
            const ushort_t* nA = srcA + (long)(tt + 1) * 16384;
            const ushort_t* nB = srcB + (long)(tt + 1) * 16384;
            STAGE_TILE(nA, nB, pb);
        }
        __builtin_amdgcn_s_setprio(1);
        MFMA16(accg, af, bg);
        MFMA16(accu, af, bu);
        __builtin_amdgcn_s_setprio(0);

        // ---- sub-step ks1: units A1/B1 (no sync needed between sub-steps) ----
#pragma unroll
        for (int mf = 0; mf < 4; ++mf) af[mf] = *(const bf16x8*)&lds[cb + 16384 + aoff[mf]];
#pragma unroll
        for (int nf = 0; nf < 4; ++nf) {
            bg[nf] = *(const bf16x8*)&lds[cb + 24576 + boff[nf]];
            bu[nf] = *(const bf16x8*)&lds[cb + 24576 + 4096 + boff[nf]];
        }
        __builtin_amdgcn_s_setprio(1);
        MFMA16(accg, af, bg);
        MFMA16(accu, af, bu);
        __builtin_amdgcn_s_setprio(0);

        asm volatile("s_waitcnt vmcnt(0)" ::: "memory");   // next tile landed (full-step cover)
        __builtin_amdgcn_s_barrier();
    }

    // epilogue: silu(g)*u -> HP packed tiles
#pragma unroll
    for (int nf = 0; nf < 4; ++nf) {
        int nloc = wc * 64 + nf * 16 + rr;
        int kt2 = nblk * 2 + (nloc >> 6);
        int k = nloc & 63;
        int kh = k >> 5, c = (k >> 3) & 3, klow = k & 7;
        ushort_t* tp = HPe + ((long)mblk * KT2 + kt2) * 16384 + kh * 8192 + klow;
#pragma unroll
        for (int mf = 0; mf < 4; ++mf)
#pragma unroll
            for (int i = 0; i < 4; ++i) {
                int m = wr * 64 + mf * 16 + g4 * 4 + i;
                int q = m >> 1;
                int pos = ((((m & 1) << 2) | c) ^ (q & 7));
                float gv = accg[mf][nf][i], uv = accu[mf][nf][i];
                float s = gv / (1.0f + __expf(-gv));
                tp[q * 64 + pos * 8] = (ushort_t)bf16rne(s * uv);
            }
    }
}

// ---------------- GEMM2: both experts, 256x256, 128KB dbuf, ONE barrier per K=64 ----------------
__global__ __launch_bounds__(512, 2)
void down8_kernel(const ushort_t* __restrict__ HP, const ushort_t* __restrict__ WPd,
                  float* __restrict__ Out) {
    __shared__ ushort_t lds[65536];     // 2 buf x {A0|B0|A1|B1}
    int nwg = gridDim.x;                // 256
    int cpx = nwg >> 3;
    int sw  = (blockIdx.x & 7) * cpx + (blockIdx.x >> 3);
    int mblk = sw & 15;                 // 0..15 (expert = mblk>>3)
    int nblk = sw >> 4;                 // 0..15
    const int t = threadIdx.x, lane = t & 63, w = t >> 6;
    const int wr = w >> 2, wc = w & 3;  // 2M x 4N waves, per-wave out 128x64
    const int rr = lane & 15, g4 = lane >> 4;
    const int so = w * 512;

    int aoff[8], boff[4];
#pragma unroll
    for (int mf = 0; mf < 8; ++mf) {
        int m = wr * 128 + mf * 16 + rr, q = m >> 1;
        aoff[mf] = q * 64 + ((((((m & 1) << 2) | g4) ^ (q & 7))) << 3);
    }
#pragma unroll
    for (int nf = 0; nf < 4; ++nf) {
        int n = wc * 64 + nf * 16 + rr, q = n >> 1;
        boff[nf] = q * 64 + ((((((n & 1) << 2) | g4) ^ (q & 7))) << 3);
    }

    f32x4 acc[8][4] = {};
    const ushort_t* srcA = HP  + (long)mblk * KT2 * 16384;
    const ushort_t* srcB = WPd + (long)(((mblk >> 3) << 4) + nblk) * KT2 * 16384;

    STAGE_TILE(srcA, srcB, 0);
    asm volatile("s_waitcnt vmcnt(0)" ::: "memory");
    __builtin_amdgcn_s_barrier();

    for (int tt = 0; tt < KT2; ++tt) {
        const int cb = (tt & 1) << 15;
        const int pb = cb ^ 32768;
        bf16x8 af[8], bf[4];

        // ---- sub-step ks0 ----
#pragma unroll
        for (int mf = 0; mf < 8; ++mf) af[mf] = *(const bf16x8*)&lds[cb + aoff[mf]];
#pragma unroll
        for (int nf = 0; nf < 4; ++nf) bf[nf] = *(const bf16x8*)&lds[cb + 8192 + boff[nf]];
        if (tt + 1 < KT2) {
            const ushort_t* nA = srcA + (long)(tt + 1) * 16384;
            const ushort_t* nB = srcB + (long)(tt + 1) * 16384;
            STAGE_TILE(nA, nB, pb);
        }
        __builtin_amdgcn_s_setprio(1);
#pragma unroll
        for (int mf = 0; mf < 8; ++mf)
#pragma unroll
            for (int nf = 0; nf < 4; ++nf)
                acc[mf][nf] = __builtin_amdgcn_mfma_f32_16x16x32_bf16(af[mf], bf[nf], acc[mf][nf], 0, 0, 0);
        __builtin_amdgcn_s_setprio(0);

        // ---- sub-step ks1 ----
#pragma unroll
        for (int mf = 0; mf < 8; ++mf) af[mf] = *(const bf16x8*)&lds[cb + 16384 + aoff[mf]];
#pragma unroll
        for (int nf = 0; nf < 4; ++nf) bf[nf] = *(const bf16x8*)&lds[cb + 24576 + boff[nf]];
        __builtin_amdgcn_s_setprio(1);
#pragma unroll
        for (int mf = 0; mf < 8; ++mf)
#pragma unroll
            for (int nf = 0; nf < 4; ++nf)
                acc[mf][nf] = __builtin_amdgcn_mfma_f32_16x16x32_bf16(af[mf], bf[nf], acc[mf][nf], 0, 0, 0);
        __builtin_amdgcn_s_setprio(0);

        asm volatile("s_waitcnt vmcnt(0)" ::: "memory");
        __builtin_amdgcn_s_barrier();
    }

#pragma unroll
    for (int mf = 0; mf < 8; ++mf)
#pragma unroll
        for (int nf = 0; nf < 4; ++nf)
#pragma unroll
            for (int i = 0; i < 4; ++i) {
                int m = mblk * 256 + wr * 128 + mf * 16 + g4 * 4 + i;
                int n = nblk * 256 + wc * 64 + nf * 16 + rr;
                Out[(long)m * HDIM + n] = acc[mf][nf][i];
            }
}

// ---------------- GEMM2 tier-2: per-expert 256x128 (round-4, proven) ----------------
__global__ __launch_bounds__(512, 2)
void down3_kernel(const ushort_t* __restrict__ HP, const ushort_t* __restrict__ WP,
                  float* __restrict__ Out) {
    __shared__ ushort_t lds[49152];
    int nwg = gridDim.x;
    int cpx = nwg >> 3;
    int sw  = (blockIdx.x & 7) * cpx + (blockIdx.x >> 3);
    int mblk = sw & 7;
    int nblk = sw >> 3;
    const int t = threadIdx.x, lane = t & 63, w = t >> 6;
    const int wr = w >> 1, wc = w & 1;
    const int rr = lane & 15, g4 = lane >> 4;
    const int so = w * 512;

    int aoff[4], boff[4];
#pragma unroll
    for (int mf = 0; mf < 4; ++mf) {
        int m = wr * 64 + mf * 16 + rr, q = m >> 1;
        aoff[mf] = q * 64 + ((((((m & 1) << 2) | g4) ^ (q & 7))) << 3);
    }
#pragma unroll
    for (int nf = 0; nf < 4; ++nf) {
        int n = wc * 64 + nf * 16 + rr, q = n >> 1;
        boff[nf] = q * 64 + ((((((n & 1) << 2) | g4) ^ (q & 7))) << 3);
    }

    f32x4 acc[4][4] = {};
    const ushort_t* srcA = HP + (long)mblk * KT2 * 16384;
    const ushort_t* srcB = WP + (long)nblk * KT2 * 8192;

    STAGE_U(srcA, 0);
    STAGE_U(srcA + 8192, 8192);
    STAGE_U(srcB, 16384);
    asm volatile("s_waitcnt vmcnt(0)" ::: "memory");
    __builtin_amdgcn_s_barrier();

    int cur = 0;
    for (int kt = 0; kt < KT2; ++kt) {
        const int cb = cur * 24576, pb = (cur ^ 1) * 24576;
        const ushort_t* nA = srcA + (long)(kt + 1) * 16384;
        const ushort_t* nB = srcB + (long)(kt + 1) * 8192;
        const bool pf = (kt + 1 < KT2);
        bf16x8 af[4], bfr[4];

#pragma unroll
        for (int mf = 0; mf < 4; ++mf) af[mf] = *(const bf16x8*)&lds[cb + aoff[mf]];
#pragma unroll
        for (int nf = 0; nf < 4; ++nf) bfr[nf] = *(const bf16x8*)&lds[cb + 16384 + boff[nf]];
        if (pf) { STAGE_U(nA, pb); STAGE_U(nB, pb + 16384); }
        __builtin_amdgcn_s_barrier();
        __builtin_amdgcn_s_setprio(1);
        MFMA16(acc, af, bfr);
        __builtin_amdgcn_s_setprio(0);
        VMCNT_MID(4);
        __builtin_amdgcn_s_barrier();

#pragma unroll
        for (int mf = 0; mf < 4; ++mf) af[mf] = *(const bf16x8*)&lds[cb + 8192 + aoff[mf]];
#pragma unroll
        for (int nf = 0; nf < 4; ++nf) bfr[nf] = *(const bf16x8*)&lds[cb + 20480 + boff[nf]];
        if (pf) STAGE_U(nA + 8192, pb + 8192);
        __builtin_amdgcn_s_barrier();
        __builtin_amdgcn_s_setprio(1);
        MFMA16(acc, af, bfr);
        __builtin_amdgcn_s_setprio(0);
        VMCNT_END(2);
        __builtin_amdgcn_s_barrier();

        cur ^= 1;
    }

#pragma unroll
    for (int mf = 0; mf < 4; ++mf)
#pragma unroll
        for (int nf = 0; nf < 4; ++nf)
#pragma unroll
            for (int i = 0; i < 4; ++i) {
                int m = mblk * 256 + wr * 64 + mf * 16 + g4 * 4 + i;
                int n = nblk * 128 + wc * 64 + nf * 16 + rr;
                Out[(long)m * HDIM + n] = acc[mf][nf][i];
            }
}

// ================= host =================
extern "C" void kernel_launch(void* const* d_in, const int* in_sizes, int n_in,
                              void* d_out, int out_size, void* d_ws, size_t ws_size,
                              hipStream_t stream) {
    const float* x     = (const float*)d_in[0];
    const float* Wgu_l = (const float*)d_in[3];
    const float* Wd_l  = (const float*)d_in[4];
    const float* Wgu_v = (const float*)d_in[5];
    const float* Wd_v  = (const float*)d_in[6];
    float* out         = (float*)d_out;

    const size_t XP_B  = (size_t)8 * KT1 * 32768;        //  16.8 MB / expert
    const size_t HP_B  = (size_t)8 * KT2 * 32768;        //  45.1 MB / expert
    const size_t WP_B  = (size_t)NB1 * KT1 * 32768;      // 180.4 MB / expert
    const size_t NEED0 = 2 * XP_B + 2 * HP_B + 2 * WP_B; // 484.6 MB
    const size_t NEED1 = XP_B + 2 * HP_B + WP_B;         // 287.4 MB (proven available)

    if (ws_size >= NEED0) {
        // tier-0: both Wgu packs resident; single 1376-block gu launch
        ushort_t* XP = (ushort_t*)d_ws;
        ushort_t* HP = XP + 2 * XPE_SH;
        ushort_t* WP = HP + 2 * HPE_SH;
        for (int e = 0; e < 2; ++e) {
            conv_x  <<<dim3(16 * KT1),      dim3(256), 0, stream>>>(
                x + (long)e * MTOK * HDIM, XP + (long)e * XPE_SH);
            conv_wgu<<<dim3(NB1 * KT1 * 2), dim3(256), 0, stream>>>(
                e ? Wgu_v : Wgu_l, WP + (long)e * WPE_SH);
        }
        gu16_kernel<<<dim3(16 * NB1), dim3(512), 0, stream>>>(XP, WP, HP, 8 * NB1);
        conv_wd2b<<<dim3(32 * KT2), dim3(256), 0, stream>>>(Wd_l, Wd_v, WP);
        down8_kernel<<<dim3(256), dim3(512), 0, stream>>>(HP, WP, out);
    } else if (ws_size >= NEED1) {
        // tier-1: per-expert gu launches
        ushort_t* XP = (ushort_t*)d_ws;
        ushort_t* HP = XP + XPE_SH;
        ushort_t* WP = HP + 2 * HPE_SH;
        for (int e = 0; e < 2; ++e) {
            conv_x  <<<dim3(16 * KT1),      dim3(256), 0, stream>>>(
                x + (long)e * MTOK * HDIM, XP);
            conv_wgu<<<dim3(NB1 * KT1 * 2), dim3(256), 0, stream>>>(
                e ? Wgu_v : Wgu_l, WP);
            gu16_kernel<<<dim3(8 * NB1), dim3(512), 0, stream>>>(
                XP, WP, HP + (long)e * HPE_SH, 8 * NB1);
        }
        conv_wd2b<<<dim3(32 * KT2), dim3(256), 0, stream>>>(Wd_l, Wd_v, WP);
        down8_kernel<<<dim3(256), dim3(512), 0, stream>>>(HP, WP, out);
    } else {
        // tier-2: per-expert flow (242 MB)
        ushort_t* XP = (ushort_t*)d_ws;
        ushort_t* HP = XP + XPE_SH;
        ushort_t* WP = HP + HPE_SH;
        for (int e = 0; e < 2; ++e) {
            const float* xe = x + (long)e * MTOK * HDIM;
            float*       oe = out + (long)e * MTOK * HDIM;
            conv_x  <<<dim3(16 * KT1),      dim3(256), 0, stream>>>(xe, XP);
            conv_wgu<<<dim3(NB1 * KT1 * 2), dim3(256), 0, stream>>>(e ? Wgu_v : Wgu_l, WP);
            gu16_kernel<<<dim3(8 * NB1),    dim3(512), 0, stream>>>(XP, WP, HP, 8 * NB1);
            conv_wd <<<dim3(NB2 * KT2),     dim3(256), 0, stream>>>(e ? Wd_v : Wd_l, WP);
            down3_kernel<<<dim3(8 * NB2),   dim3(512), 0, stream>>>(HP, WP, oe);
        }
    }
}

// Round 15
// 1250.190 us; speedup vs baseline: 1.0030x; 1.0030x over previous
//
#include <hip/hip_runtime.h>
#include <hip/hip_bf16.h>

// Round 15: break the read->MFMA dependency. Ring-4 LDS (4 x 32KB slots, 128KB)
// + REGISTER double-buffer of fragments: step kt runs MFMA on regs prefetched in
// step kt-1, while ds_reads fetch slot kt+1 into the other reg set and gl_lds
// stages slot kt+3. Reads and MFMA between one barrier pair are independent ->
// LDS pipe overlaps matrix pipe within each wave (prior structures serialized:
// ~1130cyc LDS + ~1241cyc MFMA per step = 53% util).
// Ledger: prologue stages slots 0-2, vmcnt(4) certifies 0,1; per step vmcnt(4)
// certifies slot kt+2 (read next step); tail vmcnt(0) at N-2. WAR: stage target
// slot kt-1 was reg-read in step kt-1, before that step's barrier. Two reg sets
// via kt+=2 unroll (static indices). Packs/convs/tiers = round 13.

#define HDIM 4096
#define IDIM 11008
#define N2   22016
#define MTOK 2048
#define KT1  64      // HDIM/64
#define KT2  172     // IDIM/64
#define NB1  86      // IDIM/128
#define NB2  32      // HDIM/128
#define NKD  344     // 2*KT2: down K-steps of 32
#define NPG  128     // 2*KT1: gu K-steps of 32

// per-expert pack strides in SHORTS (tile = 16384 shorts = 32 KB)
#define XPE_SH ((long)8 * KT1 * 16384)    //  16.8 MB
#define WPE_SH ((long)NB1 * KT1 * 16384)  // 180.4 MB
#define HPE_SH ((long)8 * KT2 * 16384)    //  45.1 MB

typedef unsigned short ushort_t;
using f32x4  = __attribute__((ext_vector_type(4))) float;
using bf16x8 = __attribute__((ext_vector_type(8))) short;
using u32x2  = __attribute__((ext_vector_type(2))) unsigned int;
using u32x4  = __attribute__((ext_vector_type(4))) unsigned int;

__device__ __forceinline__ unsigned int bf16rne(float f) {
    unsigned int u = __builtin_bit_cast(unsigned int, f);
    return (u + 0x7FFFu + ((u >> 16) & 1u)) >> 16;
}
__device__ __forceinline__ unsigned int pack2(float lo, float hi) {
    return bf16rne(lo) | (bf16rne(hi) << 16);
}
__device__ __forceinline__ void gl_lds16(const void* g, void* l) {
    __builtin_amdgcn_global_load_lds(
        (const __attribute__((address_space(1))) void*)g,
        (__attribute__((address_space(3))) void*)l, 16, 0, 0);
}

// ---------------- conversion kernels (fp32 -> packed bf16 units, proven) ----------------

__global__ __launch_bounds__(256)
void conv_x(const float* __restrict__ X, ushort_t* __restrict__ XP) {
    int bid = blockIdx.x;               // 16 mb128 * 64 kt
    int mb = bid >> 6, kt = bid & 63;
    int t = threadIdx.x;
    int r0 = t >> 4, c4 = t & 15;
    int kh = c4 >> 3, c = (c4 >> 1) & 3, lo4 = (c4 & 1) << 2;
    ushort_t* tp = XP + ((long)(mb >> 1) * KT1 + kt) * 16384 + (long)kh * 8192 + (mb & 1) * 4096;
#pragma unroll
    for (int p = 0; p < 8; ++p) {
        int rl = r0 + p * 16;
        f32x4 v = *(const f32x4*)(X + (long)(mb * 128 + rl) * HDIM + kt * 64 + c4 * 4);
        u32x2 pk = { pack2(v[0], v[1]), pack2(v[2], v[3]) };
        int q = rl >> 1;
        int pos = ((((rl & 1) << 2) | c) ^ (q & 7));
        *(u32x2*)&tp[q * 64 + pos * 8 + lo4] = pk;
    }
}

__global__ __launch_bounds__(256)
void conv_wgu(const float* __restrict__ W, ushort_t* __restrict__ WP) {
    int bid = blockIdx.x;               // nb(86)*kt(64)*e(2)
    int e = bid & 1, kt = (bid >> 1) & 63, nb = bid >> 7;
    int t = threadIdx.x;
    int kp = t >> 5, c4 = t & 31;
    const float* p = W + ((long)kt * 64 + kp * 8) * N2 + (long)e * IDIM + nb * 128 + c4 * 4;
    f32x4 v[8];
#pragma unroll
    for (int j = 0; j < 8; ++j) v[j] = *(const f32x4*)(p + (long)j * N2);
    ushort_t* tp = WP + ((long)nb * KT1 + kt) * 16384 + (long)(kp >> 2) * 8192 + e * 4096;
    int c = kp & 3;
#pragma unroll
    for (int cc = 0; cc < 4; ++cc) {
        int n = c4 * 4 + cc;
        int q = n >> 1;
        int pos = ((((n & 1) << 2) | c) ^ (q & 7));
        u32x4 pk = { pack2(v[0][cc], v[1][cc]), pack2(v[2][cc], v[3][cc]),
                     pack2(v[4][cc], v[5][cc]), pack2(v[6][cc], v[7][cc]) };
        *(u32x4*)&tp[q * 64 + pos * 8] = pk;
    }
}

__global__ __launch_bounds__(256)
void conv_wd2b(const float* __restrict__ Wl, const float* __restrict__ Wv,
               ushort_t* __restrict__ WPd) {
    int bid = blockIdx.x;               // 32*KT2
    int kt = bid % KT2, nbp = bid / KT2;
    int e = nbp >> 4, nb = nbp & 15;
    const float* W = e ? Wv : Wl;
    int t = threadIdx.x;
    int kp = t >> 5, c4 = t & 31;
    ushort_t* tp = WPd + ((long)nbp * KT2 + kt) * 16384 + (long)(kp >> 2) * 8192;
    int c = kp & 3;
#pragma unroll
    for (int h = 0; h < 2; ++h) {
        const float* p = W + ((long)kt * 64 + kp * 8) * HDIM + nb * 256 + h * 128 + c4 * 4;
        f32x4 v[8];
#pragma unroll
        for (int j = 0; j < 8; ++j) v[j] = *(const f32x4*)(p + (long)j * HDIM);
#pragma unroll
        for (int cc = 0; cc < 4; ++cc) {
            int n = h * 128 + c4 * 4 + cc;
            int q = n >> 1;
            int pos = ((((n & 1) << 2) | c) ^ (q & 7));
            u32x4 pk = { pack2(v[0][cc], v[1][cc]), pack2(v[2][cc], v[3][cc]),
                         pack2(v[4][cc], v[5][cc]), pack2(v[6][cc], v[7][cc]) };
            *(u32x4*)&tp[q * 64 + pos * 8] = pk;
        }
    }
}

__global__ __launch_bounds__(256)
void conv_wd(const float* __restrict__ W, ushort_t* __restrict__ WP) {
    int bid = blockIdx.x;               // nb(32)*kt(172)
    int kt = bid % KT2, nb = bid / KT2;
    int t = threadIdx.x;
    int kp = t >> 5, c4 = t & 31;
    const float* p = W + ((long)kt * 64 + kp * 8) * HDIM + nb * 128 + c4 * 4;
    f32x4 v[8];
#pragma unroll
    for (int j = 0; j < 8; ++j) v[j] = *(const f32x4*)(p + (long)j * HDIM);
    ushort_t* tp = WP + ((long)nb * KT2 + kt) * 8192 + (long)(kp >> 2) * 4096;
    int c = kp & 3;
#pragma unroll
    for (int cc = 0; cc < 4; ++cc) {
        int n = c4 * 4 + cc;
        int q = n >> 1;
        int pos = ((((n & 1) << 2) | c) ^ (q & 7));
        u32x4 pk = { pack2(v[0][cc], v[1][cc]), pack2(v[2][cc], v[3][cc]),
                     pack2(v[4][cc], v[5][cc]), pack2(v[6][cc], v[7][cc]) };
        *(u32x4*)&tp[q * 64 + pos * 8] = pk;
    }
}

// stage one 16KB unit (8192 shorts): 2 x global_load_lds per thread, linear dest
#define STAGE_U(SRC, DSTOFF) do { \
    gl_lds16((SRC) + so + lane * 8, &lds[(DSTOFF) + so]); \
    gl_lds16((SRC) + 4096 + so + lane * 8, &lds[(DSTOFF) + 4096 + so]); } while (0)

#define MFMA16(ACC, AF, BF) \
    _Pragma("unroll") \
    for (int mf = 0; mf < 4; ++mf) \
        _Pragma("unroll") \
        for (int nf = 0; nf < 4; ++nf) \
            ACC[mf][nf] = __builtin_amdgcn_mfma_f32_16x16x32_bf16(AF[mf], BF[nf], ACC[mf][nf], 0, 0, 0);

#define VMCNT_MID(N) do { \
    if (pf) asm volatile("s_waitcnt vmcnt(" #N ")" ::: "memory"); \
    else    asm volatile("s_waitcnt vmcnt(0)" ::: "memory"); } while (0)
#define VMCNT_END(N) do { \
    if (pf) asm volatile("s_waitcnt vmcnt(" #N ")" ::: "memory"); } while (0)

// ---------------- GEMM1: gate/up + silu, ring-4 + reg double-buffer ----------------
// step: MFMA on CUR regs (slot kt) | ds_read slot kt+1 -> NXT regs | stage slot kt+3
#define GU_STEP(KT, CA, CG, CU, NA_, NG_, NU_) do { \
    if ((KT) + 1 < NPG) { \
        const int rbs = (((KT) + 1) & 3) << 14; \
        _Pragma("unroll") for (int mf = 0; mf < 4; ++mf) NA_[mf] = *(const bf16x8*)&lds[rbs + aoff[mf]]; \
        _Pragma("unroll") for (int nf = 0; nf < 4; ++nf) { \
            NG_[nf] = *(const bf16x8*)&lds[rbs + 8192 + boff[nf]]; \
            NU_[nf] = *(const bf16x8*)&lds[rbs + 12288 + boff[nf]]; } \
    } \
    if ((KT) + 3 < NPG) { \
        const int ssb = (((KT) + 3) & 3) << 14; \
        STAGE_U(srcA + (long)((KT) + 3) * 8192, ssb); \
        STAGE_U(srcB + (long)((KT) + 3) * 8192, ssb + 8192); \
    } \
    __builtin_amdgcn_s_setprio(1); \
    MFMA16(accg, CA, CG); \
    MFMA16(accu, CA, CU); \
    __builtin_amdgcn_s_setprio(0); \
    if ((KT) + 3 < NPG)      asm volatile("s_waitcnt vmcnt(4)" ::: "memory"); \
    else if ((KT) + 2 < NPG) asm volatile("s_waitcnt vmcnt(0)" ::: "memory"); \
    __builtin_amdgcn_s_barrier(); \
} while (0)

__global__ __launch_bounds__(512, 2)
void gu17_kernel(const ushort_t* __restrict__ XP, const ushort_t* __restrict__ WP,
                 ushort_t* __restrict__ HP, int perE) {
    __shared__ ushort_t lds[65536];     // ring-4 x {A-unit 8192sh | B-unit(g|u) 8192sh}
    int nwg = gridDim.x;                // 688 or 1376 (both %8==0)
    int cpx = nwg >> 3;
    int sw  = (blockIdx.x & 7) * cpx + (blockIdx.x >> 3);
    int e   = (sw >= perE) ? 1 : 0;
    int lsw = sw - e * perE;
    int mblk = lsw & 7;                 // 0..7
    int nblk = lsw >> 3;                // 0..85
    const int t = threadIdx.x, lane = t & 63, w = t >> 6;
    const int wr = w >> 1, wc = w & 1;  // 4M x 2N waves
    const int rr = lane & 15, g4 = lane >> 4;
    const int so = w * 512;

    int aoff[4], boff[4];
#pragma unroll
    for (int mf = 0; mf < 4; ++mf) {
        int m = wr * 64 + mf * 16 + rr, q = m >> 1;
        aoff[mf] = q * 64 + ((((((m & 1) << 2) | g4) ^ (q & 7))) << 3);
    }
#pragma unroll
    for (int nf = 0; nf < 4; ++nf) {
        int n = wc * 64 + nf * 16 + rr, q = n >> 1;
        boff[nf] = q * 64 + ((((((n & 1) << 2) | g4) ^ (q & 7))) << 3);
    }

    f32x4 accg[4][4] = {}, accu[4][4] = {};
    const ushort_t* srcA = XP + (long)e * XPE_SH + (long)mblk * KT1 * 16384;
    const ushort_t* srcB = WP + (long)e * WPE_SH + (long)nblk * KT1 * 16384;
    ushort_t* HPe = HP + (long)e * HPE_SH;

    // prologue: stage slots 0,1,2; certify slots 0,1; read slot 0 -> set A
    STAGE_U(srcA, 0);                 STAGE_U(srcB, 8192);
    STAGE_U(srcA + 8192, 16384);      STAGE_U(srcB + 8192, 16384 + 8192);
    STAGE_U(srcA + 16384, 32768);     STAGE_U(srcB + 16384, 32768 + 8192);
    asm volatile("s_waitcnt vmcnt(4)" ::: "memory");   // slots 0,1 landed
    __builtin_amdgcn_s_barrier();

    bf16x8 afA[4], bgA[4], buA[4], afB[4], bgB[4], buB[4];
#pragma unroll
    for (int mf = 0; mf < 4; ++mf) afA[mf] = *(const bf16x8*)&lds[aoff[mf]];
#pragma unroll
    for (int nf = 0; nf < 4; ++nf) {
        bgA[nf] = *(const bf16x8*)&lds[8192 + boff[nf]];
        buA[nf] = *(const bf16x8*)&lds[12288 + boff[nf]];
    }

    for (int kt = 0; kt < NPG; kt += 2) {
        GU_STEP(kt,     afA, bgA, buA, afB, bgB, buB);
        GU_STEP(kt + 1, afB, bgB, buB, afA, bgA, buA);
    }

    // epilogue: silu(g)*u -> HP packed tiles
#pragma unroll
    for (int nf = 0; nf < 4; ++nf) {
        int nloc = wc * 64 + nf * 16 + rr;
        int kt2 = nblk * 2 + (nloc >> 6);
        int k = nloc & 63;
        int kh = k >> 5, c = (k >> 3) & 3, klow = k & 7;
        ushort_t* tp = HPe + ((long)mblk * KT2 + kt2) * 16384 + kh * 8192 + klow;
#pragma unroll
        for (int mf = 0; mf < 4; ++mf)
#pragma unroll
            for (int i = 0; i < 4; ++i) {
                int m = wr * 64 + mf * 16 + g4 * 4 + i;
                int q = m >> 1;
                int pos = ((((m & 1) << 2) | c) ^ (q & 7));
                float gv = accg[mf][nf][i], uv = accu[mf][nf][i];
                float s = gv / (1.0f + __expf(-gv));
                tp[q * 64 + pos * 8] = (ushort_t)bf16rne(s * uv);
            }
    }
}

// ---------------- GEMM2: both experts, 256x256, ring-4 + reg double-buffer ----------------
#define DN_STEP(KT, CA, CB, NA_, NB_) do { \
    if ((KT) + 1 < NKD) { \
        const int rbs = (((KT) + 1) & 3) << 14; \
        _Pragma("unroll") for (int mf = 0; mf < 8; ++mf) NA_[mf] = *(const bf16x8*)&lds[rbs + aoff[mf]]; \
        _Pragma("unroll") for (int nf = 0; nf < 4; ++nf) NB_[nf] = *(const bf16x8*)&lds[rbs + 8192 + boff[nf]]; \
    } \
    if ((KT) + 3 < NKD) { \
        const int ssb = (((KT) + 3) & 3) << 14; \
        STAGE_U(srcA + (long)((KT) + 3) * 8192, ssb); \
        STAGE_U(srcB + (long)((KT) + 3) * 8192, ssb + 8192); \
    } \
    __builtin_amdgcn_s_setprio(1); \
    _Pragma("unroll") for (int mf = 0; mf < 8; ++mf) \
        _Pragma("unroll") for (int nf = 0; nf < 4; ++nf) \
            acc[mf][nf] = __builtin_amdgcn_mfma_f32_16x16x32_bf16(CA[mf], CB[nf], acc[mf][nf], 0, 0, 0); \
    __builtin_amdgcn_s_setprio(0); \
    if ((KT) + 3 < NKD)      asm volatile("s_waitcnt vmcnt(4)" ::: "memory"); \
    else if ((KT) + 2 < NKD) asm volatile("s_waitcnt vmcnt(0)" ::: "memory"); \
    __builtin_amdgcn_s_barrier(); \
} while (0)

__global__ __launch_bounds__(512, 2)
void down9_kernel(const ushort_t* __restrict__ HP, const ushort_t* __restrict__ WPd,
                  float* __restrict__ Out) {
    __shared__ ushort_t lds[65536];     // ring-4 x {A-unit | B-unit}
    int nwg = gridDim.x;                // 256
    int cpx = nwg >> 3;
    int sw  = (blockIdx.x & 7) * cpx + (blockIdx.x >> 3);
    int mblk = sw & 15;                 // 0..15 (expert = mblk>>3)
    int nblk = sw >> 4;                 // 0..15
    const int t = threadIdx.x, lane = t & 63, w = t >> 6;
    const int wr = w >> 2, wc = w & 3;  // 2M x 4N waves, per-wave out 128x64
    const int rr = lane & 15, g4 = lane >> 4;
    const int so = w * 512;

    int aoff[8], boff[4];
#pragma unroll
    for (int mf = 0; mf < 8; ++mf) {
        int m = wr * 128 + mf * 16 + rr, q = m >> 1;
        aoff[mf] = q * 64 + ((((((m & 1) << 2) | g4) ^ (q & 7))) << 3);
    }
#pragma unroll
    for (int nf = 0; nf < 4; ++nf) {
        int n = wc * 64 + nf * 16 + rr, q = n >> 1;
        boff[nf] = q * 64 + ((((((n & 1) << 2) | g4) ^ (q & 7))) << 3);
    }

    f32x4 acc[8][4] = {};
    const ushort_t* srcA = HP  + (long)mblk * KT2 * 16384;
    const ushort_t* srcB = WPd + (long)(((mblk >> 3) << 4) + nblk) * KT2 * 16384;

    STAGE_U(srcA, 0);                 STAGE_U(srcB, 8192);
    STAGE_U(srcA + 8192, 16384);      STAGE_U(srcB + 8192, 16384 + 8192);
    STAGE_U(srcA + 16384, 32768);     STAGE_U(srcB + 16384, 32768 + 8192);
    asm volatile("s_waitcnt vmcnt(4)" ::: "memory");
    __builtin_amdgcn_s_barrier();

    bf16x8 afA[8], bfA[4], afB[8], bfB[4];
#pragma unroll
    for (int mf = 0; mf < 8; ++mf) afA[mf] = *(const bf16x8*)&lds[aoff[mf]];
#pragma unroll
    for (int nf = 0; nf < 4; ++nf) bfA[nf] = *(const bf16x8*)&lds[8192 + boff[nf]];

    for (int kt = 0; kt < NKD; kt += 2) {
        DN_STEP(kt,     afA, bfA, afB, bfB);
        DN_STEP(kt + 1, afB, bfB, afA, bfA);
    }

#pragma unroll
    for (int mf = 0; mf < 8; ++mf)
#pragma unroll
        for (int nf = 0; nf < 4; ++nf)
#pragma unroll
            for (int i = 0; i < 4; ++i) {
                int m = mblk * 256 + wr * 128 + mf * 16 + g4 * 4 + i;
                int n = nblk * 256 + wc * 64 + nf * 16 + rr;
                Out[(long)m * HDIM + n] = acc[mf][nf][i];
            }
}

// ---------------- GEMM2 tier-2: per-expert 256x128 (round-4, proven) ----------------
__global__ __launch_bounds__(512, 2)
void down3_kernel(const ushort_t* __restrict__ HP, const ushort_t* __restrict__ WP,
                  float* __restrict__ Out) {
    __shared__ ushort_t lds[49152];
    int nwg = gridDim.x;
    int cpx = nwg >> 3;
    int sw  = (blockIdx.x & 7) * cpx + (blockIdx.x >> 3);
    int mblk = sw & 7;
    int nblk = sw >> 3;
    const int t = threadIdx.x, lane = t & 63, w = t >> 6;
    const int wr = w >> 1, wc = w & 1;
    const int rr = lane & 15, g4 = lane >> 4;
    const int so = w * 512;

    int aoff[4], boff[4];
#pragma unroll
    for (int mf = 0; mf < 4; ++mf) {
        int m = wr * 64 + mf * 16 + rr, q = m >> 1;
        aoff[mf] = q * 64 + ((((((m & 1) << 2) | g4) ^ (q & 7))) << 3);
    }
#pragma unroll
    for (int nf = 0; nf < 4; ++nf) {
        int n = wc * 64 + nf * 16 + rr, q = n >> 1;
        boff[nf] = q * 64 + ((((((n & 1) << 2) | g4) ^ (q & 7))) << 3);
    }

    f32x4 acc[4][4] = {};
    const ushort_t* srcA = HP + (long)mblk * KT2 * 16384;
    const ushort_t* srcB = WP + (long)nblk * KT2 * 8192;

    STAGE_U(srcA, 0);
    STAGE_U(srcA + 8192, 8192);
    STAGE_U(srcB, 16384);
    asm volatile("s_waitcnt vmcnt(0)" ::: "memory");
    __builtin_amdgcn_s_barrier();

    int cur = 0;
    for (int kt = 0; kt < KT2; ++kt) {
        const int cb = cur * 24576, pb = (cur ^ 1) * 24576;
        const ushort_t* nA = srcA + (long)(kt + 1) * 16384;
        const ushort_t* nB = srcB + (long)(kt + 1) * 8192;
        const bool pf = (kt + 1 < KT2);
        bf16x8 af[4], bfr[4];

#pragma unroll
        for (int mf = 0; mf < 4; ++mf) af[mf] = *(const bf16x8*)&lds[cb + aoff[mf]];
#pragma unroll
        for (int nf = 0; nf < 4; ++nf) bfr[nf] = *(const bf16x8*)&lds[cb + 16384 + boff[nf]];
        if (pf) { STAGE_U(nA, pb); STAGE_U(nB, pb + 16384); }
        __builtin_amdgcn_s_barrier();
        __builtin_amdgcn_s_setprio(1);
        MFMA16(acc, af, bfr);
        __builtin_amdgcn_s_setprio(0);
        VMCNT_MID(4);
        __builtin_amdgcn_s_barrier();

#pragma unroll
        for (int mf = 0; mf < 4; ++mf) af[mf] = *(const bf16x8*)&lds[cb + 8192 + aoff[mf]];
#pragma unroll
        for (int nf = 0; nf < 4; ++nf) bfr[nf] = *(const bf16x8*)&lds[cb + 20480 + boff[nf]];
        if (pf) STAGE_U(nA + 8192, pb + 8192);
        __builtin_amdgcn_s_barrier();
        __builtin_amdgcn_s_setprio(1);
        MFMA16(acc, af, bfr);
        __builtin_amdgcn_s_setprio(0);
        VMCNT_END(2);
        __builtin_amdgcn_s_barrier();

        cur ^= 1;
    }

#pragma unroll
    for (int mf = 0; mf < 4; ++mf)
#pragma unroll
        for (int nf = 0; nf < 4; ++nf)
#pragma unroll
            for (int i = 0; i < 4; ++i) {
                int m = mblk * 256 + wr * 64 + mf * 16 + g4 * 4 + i;
                int n = nblk * 128 + wc * 64 + nf * 16 + rr;
                Out[(long)m * HDIM + n] = acc[mf][nf][i];
            }
}

// ================= host =================
extern "C" void kernel_launch(void* const* d_in, const int* in_sizes, int n_in,
                              void* d_out, int out_size, void* d_ws, size_t ws_size,
                              hipStream_t stream) {
    const float* x     = (const float*)d_in[0];
    const float* Wgu_l = (const float*)d_in[3];
    const float* Wd_l  = (const float*)d_in[4];
    const float* Wgu_v = (const float*)d_in[5];
    const float* Wd_v  = (const float*)d_in[6];
    float* out         = (float*)d_out;

    const size_t XP_B  = (size_t)8 * KT1 * 32768;        //  16.8 MB / expert
    const size_t HP_B  = (size_t)8 * KT2 * 32768;        //  45.1 MB / expert
    const size_t WP_B  = (size_t)NB1 * KT1 * 32768;      // 180.4 MB / expert
    const size_t NEED0 = 2 * XP_B + 2 * HP_B + 2 * WP_B; // 484.6 MB
    const size_t NEED1 = XP_B + 2 * HP_B + WP_B;         // 287.4 MB (proven available)

    if (ws_size >= NEED0) {
        ushort_t* XP = (ushort_t*)d_ws;
        ushort_t* HP = XP + 2 * XPE_SH;
        ushort_t* WP = HP + 2 * HPE_SH;
        for (int e = 0; e < 2; ++e) {
            conv_x  <<<dim3(16 * KT1),      dim3(256), 0, stream>>>(
                x + (long)e * MTOK * HDIM, XP + (long)e * XPE_SH);
            conv_wgu<<<dim3(NB1 * KT1 * 2), dim3(256), 0, stream>>>(
                e ? Wgu_v : Wgu_l, WP + (long)e * WPE_SH);
        }
        gu17_kernel<<<dim3(16 * NB1), dim3(512), 0, stream>>>(XP, WP, HP, 8 * NB1);
        conv_wd2b<<<dim3(32 * KT2), dim3(256), 0, stream>>>(Wd_l, Wd_v, WP);
        down9_kernel<<<dim3(256), dim3(512), 0, stream>>>(HP, WP, out);
    } else if (ws_size >= NEED1) {
        ushort_t* XP = (ushort_t*)d_ws;
        ushort_t* HP = XP + XPE_SH;
        ushort_t* WP = HP + 2 * HPE_SH;
        for (int e = 0; e < 2; ++e) {
            conv_x  <<<dim3(16 * KT1),      dim3(256), 0, stream>>>(
                x + (long)e * MTOK * HDIM, XP);
            conv_wgu<<<dim3(NB1 * KT1 * 2), dim3(256), 0, stream>>>(
                e ? Wgu_v : Wgu_l, WP);
            gu17_kernel<<<dim3(8 * NB1), dim3(512), 0, stream>>>(
                XP, WP, HP + (long)e * HPE_SH, 8 * NB1);
        }
        conv_wd2b<<<dim3(32 * KT2), dim3(256), 0, stream>>>(Wd_l, Wd_v, WP);
        down9_kernel<<<dim3(256), dim3(512), 0, stream>>>(HP, WP, out);
    } else {
        ushort_t* XP = (ushort_t*)d_ws;
        ushort_t* HP = XP + XPE_SH;
        ushort_t* WP = HP + HPE_SH;
        for (int e = 0; e < 2; ++e) {
            const float* xe = x + (long)e * MTOK * HDIM;
            float*       oe = out + (long)e * MTOK * HDIM;
            conv_x  <<<dim3(16 * KT1),      dim3(256), 0, stream>>>(xe, XP);
            conv_wgu<<<dim3(NB1 * KT1 * 2), dim3(256), 0, stream>>>(e ? Wgu_v : Wgu_l, WP);
            gu17_kernel<<<dim3(8 * NB1),    dim3(512), 0, stream>>>(XP, WP, HP, 8 * NB1);
            conv_wd <<<dim3(NB2 * KT2),     dim3(256), 0, stream>>>(e ? Wd_v : Wd_l, WP);
            down3_kernel<<<dim3(8 * NB2),   dim3(512), 0, stream>>>(HP, WP, oe);
        }
    }
}

// Round 16
// 1225.355 us; speedup vs baseline: 1.0234x; 1.0203x over previous
//
#include <hip/hip_runtime.h>
#include <hip/hip_bf16.h>

// Round 16: consolidation — revert to the measured-best configuration (round 13,
// 1223-1230 us). Rounds 14 (K64-dbuf, 1254) and 15 (ring-4 + reg-dbuf, 1250) both
// regressed and falsified the read->MFMA-serialization model; eight structural
// variants bracket 46-53% MfmaUtil, best = this ring-3 / one-barrier / counted
// vmcnt(4) core. Cores, packs, convs, tiers byte-identical to round 13.

#define HDIM 4096
#define IDIM 11008
#define N2   22016
#define MTOK 2048
#define KT1  64      // HDIM/64
#define KT2  172     // IDIM/64
#define NB1  86      // IDIM/128
#define NB2  32      // HDIM/128
#define NKD  344     // 2*KT2: down K-steps of 32
#define NPG  128     // 2*KT1: gu K-steps of 32

// per-expert pack strides in SHORTS (tile = 16384 shorts = 32 KB)
#define XPE_SH ((long)8 * KT1 * 16384)    //  16.8 MB
#define WPE_SH ((long)NB1 * KT1 * 16384)  // 180.4 MB
#define HPE_SH ((long)8 * KT2 * 16384)    //  45.1 MB

typedef unsigned short ushort_t;
using f32x4  = __attribute__((ext_vector_type(4))) float;
using bf16x8 = __attribute__((ext_vector_type(8))) short;
using u32x2  = __attribute__((ext_vector_type(2))) unsigned int;
using u32x4  = __attribute__((ext_vector_type(4))) unsigned int;

__device__ __forceinline__ unsigned int bf16rne(float f) {
    unsigned int u = __builtin_bit_cast(unsigned int, f);
    return (u + 0x7FFFu + ((u >> 16) & 1u)) >> 16;
}
__device__ __forceinline__ unsigned int pack2(float lo, float hi) {
    return bf16rne(lo) | (bf16rne(hi) << 16);
}
__device__ __forceinline__ void gl_lds16(const void* g, void* l) {
    __builtin_amdgcn_global_load_lds(
        (const __attribute__((address_space(1))) void*)g,
        (__attribute__((address_space(3))) void*)l, 16, 0, 0);
}

// ---------------- conversion kernels (fp32 -> packed bf16 units, proven) ----------------

__global__ __launch_bounds__(256)
void conv_x(const float* __restrict__ X, ushort_t* __restrict__ XP) {
    int bid = blockIdx.x;               // 16 mb128 * 64 kt
    int mb = bid >> 6, kt = bid & 63;
    int t = threadIdx.x;
    int r0 = t >> 4, c4 = t & 15;
    int kh = c4 >> 3, c = (c4 >> 1) & 3, lo4 = (c4 & 1) << 2;
    ushort_t* tp = XP + ((long)(mb >> 1) * KT1 + kt) * 16384 + (long)kh * 8192 + (mb & 1) * 4096;
#pragma unroll
    for (int p = 0; p < 8; ++p) {
        int rl = r0 + p * 16;
        f32x4 v = *(const f32x4*)(X + (long)(mb * 128 + rl) * HDIM + kt * 64 + c4 * 4);
        u32x2 pk = { pack2(v[0], v[1]), pack2(v[2], v[3]) };
        int q = rl >> 1;
        int pos = ((((rl & 1) << 2) | c) ^ (q & 7));
        *(u32x2*)&tp[q * 64 + pos * 8 + lo4] = pk;
    }
}

__global__ __launch_bounds__(256)
void conv_wgu(const float* __restrict__ W, ushort_t* __restrict__ WP) {
    int bid = blockIdx.x;               // nb(86)*kt(64)*e(2)
    int e = bid & 1, kt = (bid >> 1) & 63, nb = bid >> 7;
    int t = threadIdx.x;
    int kp = t >> 5, c4 = t & 31;
    const float* p = W + ((long)kt * 64 + kp * 8) * N2 + (long)e * IDIM + nb * 128 + c4 * 4;
    f32x4 v[8];
#pragma unroll
    for (int j = 0; j < 8; ++j) v[j] = *(const f32x4*)(p + (long)j * N2);
    ushort_t* tp = WP + ((long)nb * KT1 + kt) * 16384 + (long)(kp >> 2) * 8192 + e * 4096;
    int c = kp & 3;
#pragma unroll
    for (int cc = 0; cc < 4; ++cc) {
        int n = c4 * 4 + cc;
        int q = n >> 1;
        int pos = ((((n & 1) << 2) | c) ^ (q & 7));
        u32x4 pk = { pack2(v[0][cc], v[1][cc]), pack2(v[2][cc], v[3][cc]),
                     pack2(v[4][cc], v[5][cc]), pack2(v[6][cc], v[7][cc]) };
        *(u32x4*)&tp[q * 64 + pos * 8] = pk;
    }
}

// both experts in one launch
__global__ __launch_bounds__(256)
void conv_wd2b(const float* __restrict__ Wl, const float* __restrict__ Wv,
               ushort_t* __restrict__ WPd) {
    int bid = blockIdx.x;               // 32*KT2
    int kt = bid % KT2, nbp = bid / KT2;
    int e = nbp >> 4, nb = nbp & 15;
    const float* W = e ? Wv : Wl;
    int t = threadIdx.x;
    int kp = t >> 5, c4 = t & 31;
    ushort_t* tp = WPd + ((long)nbp * KT2 + kt) * 16384 + (long)(kp >> 2) * 8192;
    int c = kp & 3;
#pragma unroll
    for (int h = 0; h < 2; ++h) {
        const float* p = W + ((long)kt * 64 + kp * 8) * HDIM + nb * 256 + h * 128 + c4 * 4;
        f32x4 v[8];
#pragma unroll
        for (int j = 0; j < 8; ++j) v[j] = *(const f32x4*)(p + (long)j * HDIM);
#pragma unroll
        for (int cc = 0; cc < 4; ++cc) {
            int n = h * 128 + c4 * 4 + cc;
            int q = n >> 1;
            int pos = ((((n & 1) << 2) | c) ^ (q & 7));
            u32x4 pk = { pack2(v[0][cc], v[1][cc]), pack2(v[2][cc], v[3][cc]),
                         pack2(v[4][cc], v[5][cc]), pack2(v[6][cc], v[7][cc]) };
            *(u32x4*)&tp[q * 64 + pos * 8] = pk;
        }
    }
}

__global__ __launch_bounds__(256)
void conv_wd(const float* __restrict__ W, ushort_t* __restrict__ WP) {
    int bid = blockIdx.x;               // nb(32)*kt(172)
    int kt = bid % KT2, nb = bid / KT2;
    int t = threadIdx.x;
    int kp = t >> 5, c4 = t & 31;
    const float* p = W + ((long)kt * 64 + kp * 8) * HDIM + nb * 128 + c4 * 4;
    f32x4 v[8];
#pragma unroll
    for (int j = 0; j < 8; ++j) v[j] = *(const f32x4*)(p + (long)j * HDIM);
    ushort_t* tp = WP + ((long)nb * KT2 + kt) * 8192 + (long)(kp >> 2) * 4096;
    int c = kp & 3;
#pragma unroll
    for (int cc = 0; cc < 4; ++cc) {
        int n = c4 * 4 + cc;
        int q = n >> 1;
        int pos = ((((n & 1) << 2) | c) ^ (q & 7));
        u32x4 pk = { pack2(v[0][cc], v[1][cc]), pack2(v[2][cc], v[3][cc]),
                     pack2(v[4][cc], v[5][cc]), pack2(v[6][cc], v[7][cc]) };
        *(u32x4*)&tp[q * 64 + pos * 8] = pk;
    }
}

// stage one 16KB unit (8192 shorts): 2 x global_load_lds per thread, linear dest
#define STAGE_U(SRC, DSTOFF) do { \
    gl_lds16((SRC) + so + lane * 8, &lds[(DSTOFF) + so]); \
    gl_lds16((SRC) + 4096 + so + lane * 8, &lds[(DSTOFF) + 4096 + so]); } while (0)

#define MFMA16(ACC, AF, BF) \
    _Pragma("unroll") \
    for (int mf = 0; mf < 4; ++mf) \
        _Pragma("unroll") \
        for (int nf = 0; nf < 4; ++nf) \
            ACC[mf][nf] = __builtin_amdgcn_mfma_f32_16x16x32_bf16(AF[mf], BF[nf], ACC[mf][nf], 0, 0, 0);

#define VMCNT_MID(N) do { \
    if (pf) asm volatile("s_waitcnt vmcnt(" #N ")" ::: "memory"); \
    else    asm volatile("s_waitcnt vmcnt(0)" ::: "memory"); } while (0)
#define VMCNT_END(N) do { \
    if (pf) asm volatile("s_waitcnt vmcnt(" #N ")" ::: "memory"); } while (0)

// ---------------- GEMM1: gate/up + silu, ring-3, ONE barrier/step (round-10 core) ----------------
__global__ __launch_bounds__(512, 2)
void gu15_kernel(const ushort_t* __restrict__ XP, const ushort_t* __restrict__ WP,
                 ushort_t* __restrict__ HP, int perE) {
    __shared__ ushort_t lds[49152];     // ring-3 x [A-unit 8192sh | B-unit(g|u) 8192sh]
    int nwg = gridDim.x;                // 688 or 1376 (both %8==0)
    int cpx = nwg >> 3;
    int sw  = (blockIdx.x & 7) * cpx + (blockIdx.x >> 3);
    int e   = (sw >= perE) ? 1 : 0;
    int lsw = sw - e * perE;
    int mblk = lsw & 7;                 // 0..7
    int nblk = lsw >> 3;                // 0..85
    const int t = threadIdx.x, lane = t & 63, w = t >> 6;
    const int wr = w >> 1, wc = w & 1;  // 4M x 2N waves
    const int rr = lane & 15, g4 = lane >> 4;
    const int so = w * 512;

    int aoff[4], boff[4];
#pragma unroll
    for (int mf = 0; mf < 4; ++mf) {
        int m = wr * 64 + mf * 16 + rr, q = m >> 1;
        aoff[mf] = q * 64 + ((((((m & 1) << 2) | g4) ^ (q & 7))) << 3);
    }
#pragma unroll
    for (int nf = 0; nf < 4; ++nf) {
        int n = wc * 64 + nf * 16 + rr, q = n >> 1;
        boff[nf] = q * 64 + ((((((n & 1) << 2) | g4) ^ (q & 7))) << 3);
    }

    f32x4 accg[4][4] = {}, accu[4][4] = {};
    const ushort_t* srcA = XP + (long)e * XPE_SH + (long)mblk * KT1 * 16384;
    const ushort_t* srcB = WP + (long)e * WPE_SH + (long)nblk * KT1 * 16384;
    ushort_t* HPe = HP + (long)e * HPE_SH;

    // prologue: stage unit 0 -> slot0, unit 1 -> slot1
    STAGE_U(srcA, 0);
    STAGE_U(srcB, 8192);
    STAGE_U(srcA + 8192, 16384);
    STAGE_U(srcB + 8192, 16384 + 8192);
    asm volatile("s_waitcnt vmcnt(4)" ::: "memory");   // unit 0 landed
    __builtin_amdgcn_s_barrier();

    int cb = 0, sb = 32768;
    for (int kt = 0; kt < NPG; ++kt) {
        bf16x8 af[4], bg[4], bu[4];
#pragma unroll
        for (int mf = 0; mf < 4; ++mf) af[mf] = *(const bf16x8*)&lds[cb + aoff[mf]];
#pragma unroll
        for (int nf = 0; nf < 4; ++nf) {
            bg[nf] = *(const bf16x8*)&lds[cb + 8192 + boff[nf]];
            bu[nf] = *(const bf16x8*)&lds[cb + 8192 + 4096 + boff[nf]];
        }
        const bool pf = (kt + 2 < NPG);
        if (pf) {
            const ushort_t* nA = srcA + (long)(kt + 2) * 8192;
            const ushort_t* nB = srcB + (long)(kt + 2) * 8192;
            STAGE_U(nA, sb);
            STAGE_U(nB, sb + 8192);
        }
        // NO pre-MFMA barrier (round-10 winner): waves skew, MFMA overlaps reads
        __builtin_amdgcn_s_setprio(1);
        MFMA16(accg, af, bg);
        MFMA16(accu, af, bu);
        __builtin_amdgcn_s_setprio(0);
        if (pf)                   asm volatile("s_waitcnt vmcnt(4)" ::: "memory"); // unit kt+1 landed
        else if (kt + 1 < NPG)    asm volatile("s_waitcnt vmcnt(0)" ::: "memory"); // tail drain
        __builtin_amdgcn_s_barrier();
        sb = cb;
        cb += 16384; if (cb == 49152) cb = 0;
    }

    // epilogue: silu(g)*u -> HP packed tiles
#pragma unroll
    for (int nf = 0; nf < 4; ++nf) {
        int nloc = wc * 64 + nf * 16 + rr;
        int kt2 = nblk * 2 + (nloc >> 6);
        int k = nloc & 63;
        int kh = k >> 5, c = (k >> 3) & 3, klow = k & 7;
        ushort_t* tp = HPe + ((long)mblk * KT2 + kt2) * 16384 + kh * 8192 + klow;
#pragma unroll
        for (int mf = 0; mf < 4; ++mf)
#pragma unroll
            for (int i = 0; i < 4; ++i) {
                int m = wr * 64 + mf * 16 + g4 * 4 + i;
                int q = m >> 1;
                int pos = ((((m & 1) << 2) | c) ^ (q & 7));
                float gv = accg[mf][nf][i], uv = accu[mf][nf][i];
                float s = gv / (1.0f + __expf(-gv));
                tp[q * 64 + pos * 8] = (ushort_t)bf16rne(s * uv);
            }
    }
}

// ---------------- GEMM2 tier-0/1: both experts, 256x256, ring-3 (round-10 core) ----------------
__global__ __launch_bounds__(512, 2)
void down6_kernel(const ushort_t* __restrict__ HP, const ushort_t* __restrict__ WPd,
                  float* __restrict__ Out) {
    __shared__ ushort_t lds[49152];     // ring-3 x [A-unit 8192 | B-unit 8192]
    int nwg = gridDim.x;                // 256
    int cpx = nwg >> 3;
    int sw  = (blockIdx.x & 7) * cpx + (blockIdx.x >> 3);
    int mblk = sw & 15;                 // 0..15 (expert = mblk>>3)
    int nblk = sw >> 4;                 // 0..15
    const int t = threadIdx.x, lane = t & 63, w = t >> 6;
    const int wr = w >> 2, wc = w & 3;  // 2M x 4N waves, per-wave out 128x64
    const int rr = lane & 15, g4 = lane >> 4;
    const int so = w * 512;

    int aoff[8], boff[4];
#pragma unroll
    for (int mf = 0; mf < 8; ++mf) {
        int m = wr * 128 + mf * 16 + rr, q = m >> 1;
        aoff[mf] = q * 64 + ((((((m & 1) << 2) | g4) ^ (q & 7))) << 3);
    }
#pragma unroll
    for (int nf = 0; nf < 4; ++nf) {
        int n = wc * 64 + nf * 16 + rr, q = n >> 1;
        boff[nf] = q * 64 + ((((((n & 1) << 2) | g4) ^ (q & 7))) << 3);
    }

    f32x4 acc[8][4] = {};
    const ushort_t* srcA = HP  + (long)mblk * KT2 * 16384;
    const ushort_t* srcB = WPd + (long)(((mblk >> 3) << 4) + nblk) * KT2 * 16384;

    STAGE_U(srcA, 0);
    STAGE_U(srcB, 8192);
    STAGE_U(srcA + 8192, 16384);
    STAGE_U(srcB + 8192, 16384 + 8192);
    asm volatile("s_waitcnt vmcnt(4)" ::: "memory");
    __builtin_amdgcn_s_barrier();

    int cb = 0, sb = 32768;
    for (int kt = 0; kt < NKD; ++kt) {
        bf16x8 af[8], bf[4];
#pragma unroll
        for (int mf = 0; mf < 8; ++mf) af[mf] = *(const bf16x8*)&lds[cb + aoff[mf]];
#pragma unroll
        for (int nf = 0; nf < 4; ++nf) bf[nf] = *(const bf16x8*)&lds[cb + 8192 + boff[nf]];
        const bool pf = (kt + 2 < NKD);
        if (pf) {
            const ushort_t* nA = srcA + (long)(kt + 2) * 8192;
            const ushort_t* nB = srcB + (long)(kt + 2) * 8192;
            STAGE_U(nA, sb);
            STAGE_U(nB, sb + 8192);
        }
        // NO pre-MFMA barrier (round-10 winner)
        __builtin_amdgcn_s_setprio(1);
#pragma unroll
        for (int mf = 0; mf < 8; ++mf)
#pragma unroll
            for (int nf = 0; nf < 4; ++nf)
                acc[mf][nf] = __builtin_amdgcn_mfma_f32_16x16x32_bf16(af[mf], bf[nf], acc[mf][nf], 0, 0, 0);
        __builtin_amdgcn_s_setprio(0);
        if (pf)                   asm volatile("s_waitcnt vmcnt(4)" ::: "memory");
        else if (kt + 1 < NKD)    asm volatile("s_waitcnt vmcnt(0)" ::: "memory");
        __builtin_amdgcn_s_barrier();
        sb = cb;
        cb += 16384; if (cb == 49152) cb = 0;
    }

#pragma unroll
    for (int mf = 0; mf < 8; ++mf)
#pragma unroll
        for (int nf = 0; nf < 4; ++nf)
#pragma unroll
            for (int i = 0; i < 4; ++i) {
                int m = mblk * 256 + wr * 128 + mf * 16 + g4 * 4 + i;
                int n = nblk * 256 + wc * 64 + nf * 16 + rr;
                Out[(long)m * HDIM + n] = acc[mf][nf][i];
            }
}

// ---------------- GEMM2 tier-2: per-expert 256x128 (round-4, proven) ----------------
__global__ __launch_bounds__(512, 2)
void down3_kernel(const ushort_t* __restrict__ HP, const ushort_t* __restrict__ WP,
                  float* __restrict__ Out) {
    __shared__ ushort_t lds[49152];
    int nwg = gridDim.x;
    int cpx = nwg >> 3;
    int sw  = (blockIdx.x & 7) * cpx + (blockIdx.x >> 3);
    int mblk = sw & 7;
    int nblk = sw >> 3;
    const int t = threadIdx.x, lane = t & 63, w = t >> 6;
    const int wr = w >> 1, wc = w & 1;
    const int rr = lane & 15, g4 = lane >> 4;
    const int so = w * 512;

    int aoff[4], boff[4];
#pragma unroll
    for (int mf = 0; mf < 4; ++mf) {
        int m = wr * 64 + mf * 16 + rr, q = m >> 1;
        aoff[mf] = q * 64 + ((((((m & 1) << 2) | g4) ^ (q & 7))) << 3);
    }
#pragma unroll
    for (int nf = 0; nf < 4; ++nf) {
        int n = wc * 64 + nf * 16 + rr, q = n >> 1;
        boff[nf] = q * 64 + ((((((n & 1) << 2) | g4) ^ (q & 7))) << 3);
    }

    f32x4 acc[4][4] = {};
    const ushort_t* srcA = HP + (long)mblk * KT2 * 16384;
    const ushort_t* srcB = WP + (long)nblk * KT2 * 8192;

    STAGE_U(srcA, 0);
    STAGE_U(srcA + 8192, 8192);
    STAGE_U(srcB, 16384);
    asm volatile("s_waitcnt vmcnt(0)" ::: "memory");
    __builtin_amdgcn_s_barrier();

    int cur = 0;
    for (int kt = 0; kt < KT2; ++kt) {
        const int cb = cur * 24576, pb = (cur ^ 1) * 24576;
        const ushort_t* nA = srcA + (long)(kt + 1) * 16384;
        const ushort_t* nB = srcB + (long)(kt + 1) * 8192;
        const bool pf = (kt + 1 < KT2);
        bf16x8 af[4], bfr[4];

#pragma unroll
        for (int mf = 0; mf < 4; ++mf) af[mf] = *(const bf16x8*)&lds[cb + aoff[mf]];
#pragma unroll
        for (int nf = 0; nf < 4; ++nf) bfr[nf] = *(const bf16x8*)&lds[cb + 16384 + boff[nf]];
        if (pf) { STAGE_U(nA, pb); STAGE_U(nB, pb + 16384); }
        __builtin_amdgcn_s_barrier();
        __builtin_amdgcn_s_setprio(1);
        MFMA16(acc, af, bfr);
        __builtin_amdgcn_s_setprio(0);
        VMCNT_MID(4);
        __builtin_amdgcn_s_barrier();

#pragma unroll
        for (int mf = 0; mf < 4; ++mf) af[mf] = *(const bf16x8*)&lds[cb + 8192 + aoff[mf]];
#pragma unroll
        for (int nf = 0; nf < 4; ++nf) bfr[nf] = *(const bf16x8*)&lds[cb + 20480 + boff[nf]];
        if (pf) STAGE_U(nA + 8192, pb + 8192);
        __builtin_amdgcn_s_barrier();
        __builtin_amdgcn_s_setprio(1);
        MFMA16(acc, af, bfr);
        __builtin_amdgcn_s_setprio(0);
        VMCNT_END(2);
        __builtin_amdgcn_s_barrier();

        cur ^= 1;
    }

#pragma unroll
    for (int mf = 0; mf < 4; ++mf)
#pragma unroll
        for (int nf = 0; nf < 4; ++nf)
#pragma unroll
            for (int i = 0; i < 4; ++i) {
                int m = mblk * 256 + wr * 64 + mf * 16 + g4 * 4 + i;
                int n = nblk * 128 + wc * 64 + nf * 16 + rr;
                Out[(long)m * HDIM + n] = acc[mf][nf][i];
            }
}

// ================= host =================
extern "C" void kernel_launch(void* const* d_in, const int* in_sizes, int n_in,
                              void* d_out, int out_size, void* d_ws, size_t ws_size,
                              hipStream_t stream) {
    const float* x     = (const float*)d_in[0];
    const float* Wgu_l = (const float*)d_in[3];
    const float* Wd_l  = (const float*)d_in[4];
    const float* Wgu_v = (const float*)d_in[5];
    const float* Wd_v  = (const float*)d_in[6];
    float* out         = (float*)d_out;

    const size_t XP_B  = (size_t)8 * KT1 * 32768;        //  16.8 MB / expert
    const size_t HP_B  = (size_t)8 * KT2 * 32768;        //  45.1 MB / expert
    const size_t WP_B  = (size_t)NB1 * KT1 * 32768;      // 180.4 MB / expert
    const size_t NEED0 = 2 * XP_B + 2 * HP_B + 2 * WP_B; // 484.6 MB
    const size_t NEED1 = XP_B + 2 * HP_B + WP_B;         // 287.4 MB

    if (ws_size >= NEED0) {
        // tier-0: both Wgu packs resident; single 1376-block gu launch
        ushort_t* XP = (ushort_t*)d_ws;
        ushort_t* HP = XP + 2 * XPE_SH;
        ushort_t* WP = HP + 2 * HPE_SH;
        for (int e = 0; e < 2; ++e) {
            conv_x  <<<dim3(16 * KT1),      dim3(256), 0, stream>>>(
                x + (long)e * MTOK * HDIM, XP + (long)e * XPE_SH);
            conv_wgu<<<dim3(NB1 * KT1 * 2), dim3(256), 0, stream>>>(
                e ? Wgu_v : Wgu_l, WP + (long)e * WPE_SH);
        }
        gu15_kernel<<<dim3(16 * NB1), dim3(512), 0, stream>>>(XP, WP, HP, 8 * NB1);
        conv_wd2b<<<dim3(32 * KT2), dim3(256), 0, stream>>>(Wd_l, Wd_v, WP);
        down6_kernel<<<dim3(256), dim3(512), 0, stream>>>(HP, WP, out);
    } else if (ws_size >= NEED1) {
        // tier-1: per-expert gu launches (round-10 flow)
        ushort_t* XP = (ushort_t*)d_ws;
        ushort_t* HP = XP + XPE_SH;
        ushort_t* WP = HP + 2 * HPE_SH;
        for (int e = 0; e < 2; ++e) {
            conv_x  <<<dim3(16 * KT1),      dim3(256), 0, stream>>>(
                x + (long)e * MTOK * HDIM, XP);
            conv_wgu<<<dim3(NB1 * KT1 * 2), dim3(256), 0, stream>>>(
                e ? Wgu_v : Wgu_l, WP);
            gu15_kernel<<<dim3(8 * NB1), dim3(512), 0, stream>>>(
                XP, WP, HP + (long)e * HPE_SH, 8 * NB1);
        }
        conv_wd2b<<<dim3(32 * KT2), dim3(256), 0, stream>>>(Wd_l, Wd_v, WP);
        down6_kernel<<<dim3(256), dim3(512), 0, stream>>>(HP, WP, out);
    } else {
        // tier-2: per-expert flow (242 MB)
        ushort_t* XP = (ushort_t*)d_ws;
        ushort_t* HP = XP + XPE_SH;
        ushort_t* WP = HP + HPE_SH;
        for (int e = 0; e < 2; ++e) {
            const float* xe = x + (long)e * MTOK * HDIM;
            float*       oe = out + (long)e * MTOK * HDIM;
            conv_x  <<<dim3(16 * KT1),      dim3(256), 0, stream>>>(xe, XP);
            conv_wgu<<<dim3(NB1 * KT1 * 2), dim3(256), 0, stream>>>(e ? Wgu_v : Wgu_l, WP);
            gu15_kernel<<<dim3(8 * NB1),    dim3(512), 0, stream>>>(XP, WP, HP, 8 * NB1);
            conv_wd <<<dim3(NB2 * KT2),     dim3(256), 0, stream>>>(e ? Wd_v : Wd_l, WP);
            down3_kernel<<<dim3(8 * NB2),   dim3(512), 0, stream>>>(HP, WP, oe);
        }
    }
}

// Round 17
// 1215.202 us; speedup vs baseline: 1.0319x; 1.0084x over previous
//
#include <hip/hip_runtime.h>
#include <hip/hip_bf16.h>

// Round 17: hide conversion work inside the gu launches. Tier-0 becomes:
//   L1: conv_x(e0), conv_x(e1), conv_wgu(e0)
//   L2: gu(e0)  + attached conv_wgu(e1) slices  (16 units/block, 688*16=11008)
//   L3: gu(e1)  + attached conv_wd2b   slices  ( 8 units/block, 688*8 =5504;
//       writes WP region-0 = expert-0's dead Wgu pack, disjoint from WP1 reads)
//   L4: down6
// Removes ~190us of serial BW-bound conv from the critical path; attached conv
// rides the gu launches' idle HBM (~1.1 of 6.3 TB/s used). gu core = round-10/13
// proven (ring-3, ONE barrier/step, counted vmcnt(4)). Tier-1/2 = proven serial.

#define HDIM 4096
#define IDIM 11008
#define N2   22016
#define MTOK 2048
#define KT1  64      // HDIM/64
#define KT2  172     // IDIM/64
#define NB1  86      // IDIM/128
#define NB2  32      // HDIM/128
#define NKD  344     // 2*KT2: down K-steps of 32
#define NPG  128     // 2*KT1: gu K-steps of 32

// per-expert pack strides in SHORTS (tile = 16384 shorts = 32 KB)
#define XPE_SH ((long)8 * KT1 * 16384)    //  16.8 MB
#define WPE_SH ((long)NB1 * KT1 * 16384)  // 180.4 MB
#define HPE_SH ((long)8 * KT2 * 16384)    //  45.1 MB

typedef unsigned short ushort_t;
using f32x4  = __attribute__((ext_vector_type(4))) float;
using bf16x8 = __attribute__((ext_vector_type(8))) short;
using u32x2  = __attribute__((ext_vector_type(2))) unsigned int;
using u32x4  = __attribute__((ext_vector_type(4))) unsigned int;

__device__ __forceinline__ unsigned int bf16rne(float f) {
    unsigned int u = __builtin_bit_cast(unsigned int, f);
    return (u + 0x7FFFu + ((u >> 16) & 1u)) >> 16;
}
__device__ __forceinline__ unsigned int pack2(float lo, float hi) {
    return bf16rne(lo) | (bf16rne(hi) << 16);
}
__device__ __forceinline__ void gl_lds16(const void* g, void* l) {
    __builtin_amdgcn_global_load_lds(
        (const __attribute__((address_space(1))) void*)g,
        (__attribute__((address_space(3))) void*)l, 16, 0, 0);
}

// ---------------- conv unit bodies (256-thread units, shared by kernels & attachments) ----------------

// one conv_wgu unit: bid in [0, NB1*KT1*2)
__device__ __forceinline__ void conv_wgu_unit(const float* __restrict__ W,
                                              ushort_t* __restrict__ WP, int bid, int t) {
    int e = bid & 1, kt = (bid >> 1) & 63, nb = bid >> 7;
    int kp = t >> 5, c4 = t & 31;
    const float* p = W + ((long)kt * 64 + kp * 8) * N2 + (long)e * IDIM + nb * 128 + c4 * 4;
    f32x4 v[8];
#pragma unroll
    for (int j = 0; j < 8; ++j) v[j] = *(const f32x4*)(p + (long)j * N2);
    ushort_t* tp = WP + ((long)nb * KT1 + kt) * 16384 + (long)(kp >> 2) * 8192 + e * 4096;
    int c = kp & 3;
#pragma unroll
    for (int cc = 0; cc < 4; ++cc) {
        int n = c4 * 4 + cc;
        int q = n >> 1;
        int pos = ((((n & 1) << 2) | c) ^ (q & 7));
        u32x4 pk = { pack2(v[0][cc], v[1][cc]), pack2(v[2][cc], v[3][cc]),
                     pack2(v[4][cc], v[5][cc]), pack2(v[6][cc], v[7][cc]) };
        *(u32x4*)&tp[q * 64 + pos * 8] = pk;
    }
}

// one conv_wd2b unit: bid in [0, 32*KT2); e = expert
__device__ __forceinline__ void conv_wd2b_unit(const float* __restrict__ Wl,
                                               const float* __restrict__ Wv,
                                               ushort_t* __restrict__ WPd, int bid, int t) {
    int kt = bid % KT2, nbp = bid / KT2;
    int e = nbp >> 4, nb = nbp & 15;
    const float* W = e ? Wv : Wl;
    int kp = t >> 5, c4 = t & 31;
    ushort_t* tp = WPd + ((long)nbp * KT2 + kt) * 16384 + (long)(kp >> 2) * 8192;
    int c = kp & 3;
#pragma unroll
    for (int h = 0; h < 2; ++h) {
        const float* p = W + ((long)kt * 64 + kp * 8) * HDIM + nb * 256 + h * 128 + c4 * 4;
        f32x4 v[8];
#pragma unroll
        for (int j = 0; j < 8; ++j) v[j] = *(const f32x4*)(p + (long)j * HDIM);
#pragma unroll
        for (int cc = 0; cc < 4; ++cc) {
            int n = h * 128 + c4 * 4 + cc;
            int q = n >> 1;
            int pos = ((((n & 1) << 2) | c) ^ (q & 7));
            u32x4 pk = { pack2(v[0][cc], v[1][cc]), pack2(v[2][cc], v[3][cc]),
                         pack2(v[4][cc], v[5][cc]), pack2(v[6][cc], v[7][cc]) };
            *(u32x4*)&tp[q * 64 + pos * 8] = pk;
        }
    }
}

// ---------------- standalone conversion kernels ----------------

__global__ __launch_bounds__(256)
void conv_x(const float* __restrict__ X, ushort_t* __restrict__ XP) {
    int bid = blockIdx.x;               // 16 mb128 * 64 kt
    int mb = bid >> 6, kt = bid & 63;
    int t = threadIdx.x;
    int r0 = t >> 4, c4 = t & 15;
    int kh = c4 >> 3, c = (c4 >> 1) & 3, lo4 = (c4 & 1) << 2;
    ushort_t* tp = XP + ((long)(mb >> 1) * KT1 + kt) * 16384 + (long)kh * 8192 + (mb & 1) * 4096;
#pragma unroll
    for (int p = 0; p < 8; ++p) {
        int rl = r0 + p * 16;
        f32x4 v = *(const f32x4*)(X + (long)(mb * 128 + rl) * HDIM + kt * 64 + c4 * 4);
        u32x2 pk = { pack2(v[0], v[1]), pack2(v[2], v[3]) };
        int q = rl >> 1;
        int pos = ((((rl & 1) << 2) | c) ^ (q & 7));
        *(u32x2*)&tp[q * 64 + pos * 8 + lo4] = pk;
    }
}

__global__ __launch_bounds__(256)
void conv_wgu(const float* __restrict__ W, ushort_t* __restrict__ WP) {
    conv_wgu_unit(W, WP, blockIdx.x, threadIdx.x);
}

__global__ __launch_bounds__(256)
void conv_wd2b(const float* __restrict__ Wl, const float* __restrict__ Wv,
               ushort_t* __restrict__ WPd) {
    conv_wd2b_unit(Wl, Wv, WPd, blockIdx.x, threadIdx.x);
}

__global__ __launch_bounds__(256)
void conv_wd(const float* __restrict__ W, ushort_t* __restrict__ WP) {
    int bid = blockIdx.x;               // nb(32)*kt(172)
    int kt = bid % KT2, nb = bid / KT2;
    int t = threadIdx.x;
    int kp = t >> 5, c4 = t & 31;
    const float* p = W + ((long)kt * 64 + kp * 8) * HDIM + nb * 128 + c4 * 4;
    f32x4 v[8];
#pragma unroll
    for (int j = 0; j < 8; ++j) v[j] = *(const f32x4*)(p + (long)j * HDIM);
    ushort_t* tp = WP + ((long)nb * KT2 + kt) * 8192 + (long)(kp >> 2) * 4096;
    int c = kp & 3;
#pragma unroll
    for (int cc = 0; cc < 4; ++cc) {
        int n = c4 * 4 + cc;
        int q = n >> 1;
        int pos = ((((n & 1) << 2) | c) ^ (q & 7));
        u32x4 pk = { pack2(v[0][cc], v[1][cc]), pack2(v[2][cc], v[3][cc]),
                     pack2(v[4][cc], v[5][cc]), pack2(v[6][cc], v[7][cc]) };
        *(u32x4*)&tp[q * 64 + pos * 8] = pk;
    }
}

// stage one 16KB unit (8192 shorts): 2 x global_load_lds per thread, linear dest
#define STAGE_U(SRC, DSTOFF) do { \
    gl_lds16((SRC) + so + lane * 8, &lds[(DSTOFF) + so]); \
    gl_lds16((SRC) + 4096 + so + lane * 8, &lds[(DSTOFF) + 4096 + so]); } while (0)

#define MFMA16(ACC, AF, BF) \
    _Pragma("unroll") \
    for (int mf = 0; mf < 4; ++mf) \
        _Pragma("unroll") \
        for (int nf = 0; nf < 4; ++nf) \
            ACC[mf][nf] = __builtin_amdgcn_mfma_f32_16x16x32_bf16(AF[mf], BF[nf], ACC[mf][nf], 0, 0, 0);

#define VMCNT_MID(N) do { \
    if (pf) asm volatile("s_waitcnt vmcnt(" #N ")" ::: "memory"); \
    else    asm volatile("s_waitcnt vmcnt(0)" ::: "memory"); } while (0)
#define VMCNT_END(N) do { \
    if (pf) asm volatile("s_waitcnt vmcnt(" #N ")" ::: "memory"); } while (0)

// ---------------- GEMM1: gate/up + silu, ring-3, ONE barrier/step + attached conv ----------------
// convMode: 0 none; 1 conv_wgu slices (cwA -> cdst); 2 conv_wd2b slices (cwA,cwB -> cdst)
__global__ __launch_bounds__(512, 2)
void gu18_kernel(const ushort_t* __restrict__ XPe, const ushort_t* __restrict__ WPe,
                 ushort_t* __restrict__ HPe, int convMode,
                 const float* __restrict__ cwA, const float* __restrict__ cwB,
                 ushort_t* __restrict__ cdst) {
    __shared__ ushort_t lds[49152];     // ring-3 x [A-unit 8192sh | B-unit(g|u) 8192sh]
    int nwg = gridDim.x;                // 688
    int cpx = nwg >> 3;
    int sw  = (blockIdx.x & 7) * cpx + (blockIdx.x >> 3);
    int mblk = sw & 7;                  // 0..7
    int nblk = sw >> 3;                 // 0..85
    const int t = threadIdx.x, lane = t & 63, w = t >> 6;
    const int wr = w >> 1, wc = w & 1;  // 4M x 2N waves
    const int rr = lane & 15, g4 = lane >> 4;
    const int so = w * 512;

    int aoff[4], boff[4];
#pragma unroll
    for (int mf = 0; mf < 4; ++mf) {
        int m = wr * 64 + mf * 16 + rr, q = m >> 1;
        aoff[mf] = q * 64 + ((((((m & 1) << 2) | g4) ^ (q & 7))) << 3);
    }
#pragma unroll
    for (int nf = 0; nf < 4; ++nf) {
        int n = wc * 64 + nf * 16 + rr, q = n >> 1;
        boff[nf] = q * 64 + ((((((n & 1) << 2) | g4) ^ (q & 7))) << 3);
    }

    f32x4 accg[4][4] = {}, accu[4][4] = {};
    const ushort_t* srcA = XPe + (long)mblk * KT1 * 16384;
    const ushort_t* srcB = WPe + (long)nblk * KT1 * 16384;

    // prologue: stage unit 0 -> slot0, unit 1 -> slot1
    STAGE_U(srcA, 0);
    STAGE_U(srcB, 8192);
    STAGE_U(srcA + 8192, 16384);
    STAGE_U(srcB + 8192, 16384 + 8192);
    asm volatile("s_waitcnt vmcnt(4)" ::: "memory");   // unit 0 landed
    __builtin_amdgcn_s_barrier();

    int cb = 0, sb = 32768;
    for (int kt = 0; kt < NPG; ++kt) {
        bf16x8 af[4], bg[4], bu[4];
#pragma unroll
        for (int mf = 0; mf < 4; ++mf) af[mf] = *(const bf16x8*)&lds[cb + aoff[mf]];
#pragma unroll
        for (int nf = 0; nf < 4; ++nf) {
            bg[nf] = *(const bf16x8*)&lds[cb + 8192 + boff[nf]];
            bu[nf] = *(const bf16x8*)&lds[cb + 8192 + 4096 + boff[nf]];
        }
        const bool pf = (kt + 2 < NPG);
        if (pf) {
            const ushort_t* nA = srcA + (long)(kt + 2) * 8192;
            const ushort_t* nB = srcB + (long)(kt + 2) * 8192;
            STAGE_U(nA, sb);
            STAGE_U(nB, sb + 8192);
        }
        // NO pre-MFMA barrier (round-10 winner): waves skew, MFMA overlaps reads
        __builtin_amdgcn_s_setprio(1);
        MFMA16(accg, af, bg);
        MFMA16(accu, af, bu);
        __builtin_amdgcn_s_setprio(0);
        if (pf)                   asm volatile("s_waitcnt vmcnt(4)" ::: "memory");
        else if (kt + 1 < NPG)    asm volatile("s_waitcnt vmcnt(0)" ::: "memory");
        __builtin_amdgcn_s_barrier();
        sb = cb;
        cb += 16384; if (cb == 49152) cb = 0;
    }

    // epilogue: silu(g)*u -> HP packed tiles
#pragma unroll
    for (int nf = 0; nf < 4; ++nf) {
        int nloc = wc * 64 + nf * 16 + rr;
        int kt2 = nblk * 2 + (nloc >> 6);
        int k = nloc & 63;
        int kh = k >> 5, c = (k >> 3) & 3, klow = k & 7;
        ushort_t* tp = HPe + ((long)mblk * KT2 + kt2) * 16384 + kh * 8192 + klow;
#pragma unroll
        for (int mf = 0; mf < 4; ++mf)
#pragma unroll
            for (int i = 0; i < 4; ++i) {
                int m = wr * 64 + mf * 16 + g4 * 4 + i;
                int q = m >> 1;
                int pos = ((((m & 1) << 2) | c) ^ (q & 7));
                float gv = accg[mf][nf][i], uv = accu[mf][nf][i];
                float s = gv / (1.0f + __expf(-gv));
                tp[q * 64 + pos * 8] = (ushort_t)bf16rne(s * uv);
            }
    }

    // attached conv slices (BW-bound; rides other CUs' gu compute)
    if (convMode == 1) {
        int tl = t & 255, half = t >> 8;
        int base = sw * 16;                 // 688*16 = 11008 units exactly
#pragma unroll 2
        for (int i = 0; i < 8; ++i)
            conv_wgu_unit(cwA, cdst, base + i * 2 + half, tl);
    } else if (convMode == 2) {
        int tl = t & 255, half = t >> 8;
        int base = sw * 8;                  // 688*8 = 5504 units exactly
#pragma unroll 2
        for (int i = 0; i < 4; ++i)
            conv_wd2b_unit(cwA, cwB, cdst, base + i * 2 + half, tl);
    }
}

// ---------------- GEMM2: both experts, 256x256, ring-3 (round-10 core, proven) ----------------
__global__ __launch_bounds__(512, 2)
void down6_kernel(const ushort_t* __restrict__ HP, const ushort_t* __restrict__ WPd,
                  float* __restrict__ Out) {
    __shared__ ushort_t lds[49152];     // ring-3 x [A-unit 8192 | B-unit 8192]
    int nwg = gridDim.x;                // 256
    int cpx = nwg >> 3;
    int sw  = (blockIdx.x & 7) * cpx + (blockIdx.x >> 3);
    int mblk = sw & 15;                 // 0..15 (expert = mblk>>3)
    int nblk = sw >> 4;                 // 0..15
    const int t = threadIdx.x, lane = t & 63, w = t >> 6;
    const int wr = w >> 2, wc = w & 3;  // 2M x 4N waves, per-wave out 128x64
    const int rr = lane & 15, g4 = lane >> 4;
    const int so = w * 512;

    int aoff[8], boff[4];
#pragma unroll
    for (int mf = 0; mf < 8; ++mf) {
        int m = wr * 128 + mf * 16 + rr, q = m >> 1;
        aoff[mf] = q * 64 + ((((((m & 1) << 2) | g4) ^ (q & 7))) << 3);
    }
#pragma unroll
    for (int nf = 0; nf < 4; ++nf) {
        int n = wc * 64 + nf * 16 + rr, q = n >> 1;
        boff[nf] = q * 64 + ((((((n & 1) << 2) | g4) ^ (q & 7))) << 3);
    }

    f32x4 acc[8][4] = {};
    const ushort_t* srcA = HP  + (long)mblk * KT2 * 16384;
    const ushort_t* srcB = WPd + (long)(((mblk >> 3) << 4) + nblk) * KT2 * 16384;

    STAGE_U(srcA, 0);
    STAGE_U(srcB, 8192);
    STAGE_U(srcA + 8192, 16384);
    STAGE_U(srcB + 8192, 16384 + 8192);
    asm volatile("s_waitcnt vmcnt(4)" ::: "memory");
    __builtin_amdgcn_s_barrier();

    int cb = 0, sb = 32768;
    for (int kt = 0; kt < NKD; ++kt) {
        bf16x8 af[8], bf[4];
#pragma unroll
        for (int mf = 0; mf < 8; ++mf) af[mf] = *(const bf16x8*)&lds[cb + aoff[mf]];
#pragma unroll
        for (int nf = 0; nf < 4; ++nf) bf[nf] = *(const bf16x8*)&lds[cb + 8192 + boff[nf]];
        const bool pf = (kt + 2 < NKD);
        if (pf) {
            const ushort_t* nA = srcA + (long)(kt + 2) * 8192;
            const ushort_t* nB = srcB + (long)(kt + 2) * 8192;
            STAGE_U(nA, sb);
            STAGE_U(nB, sb + 8192);
        }
        __builtin_amdgcn_s_setprio(1);
#pragma unroll
        for (int mf = 0; mf < 8; ++mf)
#pragma unroll
            for (int nf = 0; nf < 4; ++nf)
                acc[mf][nf] = __builtin_amdgcn_mfma_f32_16x16x32_bf16(af[mf], bf[nf], acc[mf][nf], 0, 0, 0);
        __builtin_amdgcn_s_setprio(0);
        if (pf)                   asm volatile("s_waitcnt vmcnt(4)" ::: "memory");
        else if (kt + 1 < NKD)    asm volatile("s_waitcnt vmcnt(0)" ::: "memory");
        __builtin_amdgcn_s_barrier();
        sb = cb;
        cb += 16384; if (cb == 49152) cb = 0;
    }

#pragma unroll
    for (int mf = 0; mf < 8; ++mf)
#pragma unroll
        for (int nf = 0; nf < 4; ++nf)
#pragma unroll
            for (int i = 0; i < 4; ++i) {
                int m = mblk * 256 + wr * 128 + mf * 16 + g4 * 4 + i;
                int n = nblk * 256 + wc * 64 + nf * 16 + rr;
                Out[(long)m * HDIM + n] = acc[mf][nf][i];
            }
}

// ---------------- GEMM2 tier-2: per-expert 256x128 (round-4, proven) ----------------
__global__ __launch_bounds__(512, 2)
void down3_kernel(const ushort_t* __restrict__ HP, const ushort_t* __restrict__ WP,
                  float* __restrict__ Out) {
    __shared__ ushort_t lds[49152];
    int nwg = gridDim.x;
    int cpx = nwg >> 3;
    int sw  = (blockIdx.x & 7) * cpx + (blockIdx.x >> 3);
    int mblk = sw & 7;
    int nblk = sw >> 3;
    const int t = threadIdx.x, lane = t & 63, w = t >> 6;
    const int wr = w >> 1, wc = w & 1;
    const int rr = lane & 15, g4 = lane >> 4;
    const int so = w * 512;

    int aoff[4], boff[4];
#pragma unroll
    for (int mf = 0; mf < 4; ++mf) {
        int m = wr * 64 + mf * 16 + rr, q = m >> 1;
        aoff[mf] = q * 64 + ((((((m & 1) << 2) | g4) ^ (q & 7))) << 3);
    }
#pragma unroll
    for (int nf = 0; nf < 4; ++nf) {
        int n = wc * 64 + nf * 16 + rr, q = n >> 1;
        boff[nf] = q * 64 + ((((((n & 1) << 2) | g4) ^ (q & 7))) << 3);
    }

    f32x4 acc[4][4] = {};
    const ushort_t* srcA = HP + (long)mblk * KT2 * 16384;
    const ushort_t* srcB = WP + (long)nblk * KT2 * 8192;

    STAGE_U(srcA, 0);
    STAGE_U(srcA + 8192, 8192);
    STAGE_U(srcB, 16384);
    asm volatile("s_waitcnt vmcnt(0)" ::: "memory");
    __builtin_amdgcn_s_barrier();

    int cur = 0;
    for (int kt = 0; kt < KT2; ++kt) {
        const int cb = cur * 24576, pb = (cur ^ 1) * 24576;
        const ushort_t* nA = srcA + (long)(kt + 1) * 16384;
        const ushort_t* nB = srcB + (long)(kt + 1) * 8192;
        const bool pf = (kt + 1 < KT2);
        bf16x8 af[4], bfr[4];

#pragma unroll
        for (int mf = 0; mf < 4; ++mf) af[mf] = *(const bf16x8*)&lds[cb + aoff[mf]];
#pragma unroll
        for (int nf = 0; nf < 4; ++nf) bfr[nf] = *(const bf16x8*)&lds[cb + 16384 + boff[nf]];
        if (pf) { STAGE_U(nA, pb); STAGE_U(nB, pb + 16384); }
        __builtin_amdgcn_s_barrier();
        __builtin_amdgcn_s_setprio(1);
        MFMA16(acc, af, bfr);
        __builtin_amdgcn_s_setprio(0);
        VMCNT_MID(4);
        __builtin_amdgcn_s_barrier();

#pragma unroll
        for (int mf = 0; mf < 4; ++mf) af[mf] = *(const bf16x8*)&lds[cb + 8192 + aoff[mf]];
#pragma unroll
        for (int nf = 0; nf < 4; ++nf) bfr[nf] = *(const bf16x8*)&lds[cb + 20480 + boff[nf]];
        if (pf) STAGE_U(nA + 8192, pb + 8192);
        __builtin_amdgcn_s_barrier();
        __builtin_amdgcn_s_setprio(1);
        MFMA16(acc, af, bfr);
        __builtin_amdgcn_s_setprio(0);
        VMCNT_END(2);
        __builtin_amdgcn_s_barrier();

        cur ^= 1;
    }

#pragma unroll
    for (int mf = 0; mf < 4; ++mf)
#pragma unroll
        for (int nf = 0; nf < 4; ++nf)
#pragma unroll
            for (int i = 0; i < 4; ++i) {
                int m = mblk * 256 + wr * 64 + mf * 16 + g4 * 4 + i;
                int n = nblk * 128 + wc * 64 + nf * 16 + rr;
                Out[(long)m * HDIM + n] = acc[mf][nf][i];
            }
}

// ================= host =================
extern "C" void kernel_launch(void* const* d_in, const int* in_sizes, int n_in,
                              void* d_out, int out_size, void* d_ws, size_t ws_size,
                              hipStream_t stream) {
    const float* x     = (const float*)d_in[0];
    const float* Wgu_l = (const float*)d_in[3];
    const float* Wd_l  = (const float*)d_in[4];
    const float* Wgu_v = (const float*)d_in[5];
    const float* Wd_v  = (const float*)d_in[6];
    float* out         = (float*)d_out;

    const size_t XP_B  = (size_t)8 * KT1 * 32768;        //  16.8 MB / expert
    const size_t HP_B  = (size_t)8 * KT2 * 32768;        //  45.1 MB / expert
    const size_t WP_B  = (size_t)NB1 * KT1 * 32768;      // 180.4 MB / expert
    const size_t NEED0 = 2 * XP_B + 2 * HP_B + 2 * WP_B; // 484.6 MB
    const size_t NEED1 = XP_B + 2 * HP_B + WP_B;         // 287.4 MB

    if (ws_size >= NEED0) {
        // tier-0: producer-attached convs
        ushort_t* XP = (ushort_t*)d_ws;
        ushort_t* HP = XP + 2 * XPE_SH;
        ushort_t* WP = HP + 2 * HPE_SH;
        // L1: x packs (both) + expert-0 Wgu pack
        conv_x  <<<dim3(16 * KT1),      dim3(256), 0, stream>>>(x, XP);
        conv_x  <<<dim3(16 * KT1),      dim3(256), 0, stream>>>(x + (long)MTOK * HDIM, XP + XPE_SH);
        conv_wgu<<<dim3(NB1 * KT1 * 2), dim3(256), 0, stream>>>(Wgu_l, WP);
        // L2: gu(e0) + attached conv_wgu(e1) -> WP region 1
        gu18_kernel<<<dim3(8 * NB1), dim3(512), 0, stream>>>(
            XP, WP, HP, 1, Wgu_v, nullptr, WP + WPE_SH);
        // L3: gu(e1) + attached conv_wd2b (both experts) -> WP region 0 (e0's dead Wgu pack)
        gu18_kernel<<<dim3(8 * NB1), dim3(512), 0, stream>>>(
            XP + XPE_SH, WP + WPE_SH, HP + HPE_SH, 2, Wd_l, Wd_v, WP);
        // L4: down (reads WPd = WP region 0)
        down6_kernel<<<dim3(256), dim3(512), 0, stream>>>(HP, WP, out);
    } else if (ws_size >= NEED1) {
        // tier-1: proven serial flow (round-13)
        ushort_t* XP = (ushort_t*)d_ws;
        ushort_t* HP = XP + XPE_SH;
        ushort_t* WP = HP + 2 * HPE_SH;
        for (int e = 0; e < 2; ++e) {
            conv_x  <<<dim3(16 * KT1),      dim3(256), 0, stream>>>(
                x + (long)e * MTOK * HDIM, XP);
            conv_wgu<<<dim3(NB1 * KT1 * 2), dim3(256), 0, stream>>>(
                e ? Wgu_v : Wgu_l, WP);
            gu18_kernel<<<dim3(8 * NB1), dim3(512), 0, stream>>>(
                XP, WP, HP + (long)e * HPE_SH, 0, nullptr, nullptr, nullptr);
        }
        conv_wd2b<<<dim3(32 * KT2), dim3(256), 0, stream>>>(Wd_l, Wd_v, WP);
        down6_kernel<<<dim3(256), dim3(512), 0, stream>>>(HP, WP, out);
    } else {
        // tier-2: per-expert flow (242 MB)
        ushort_t* XP = (ushort_t*)d_ws;
        ushort_t* HP = XP + XPE_SH;
        ushort_t* WP = HP + HPE_SH;
        for (int e = 0; e < 2; ++e) {
            const float* xe = x + (long)e * MTOK * HDIM;
            float*       oe = out + (long)e * MTOK * HDIM;
            conv_x  <<<dim3(16 * KT1),      dim3(256), 0, stream>>>(xe, XP);
            conv_wgu<<<dim3(NB1 * KT1 * 2), dim3(256), 0, stream>>>(e ? Wgu_v : Wgu_l, WP);
            gu18_kernel<<<dim3(8 * NB1),    dim3(512), 0, stream>>>(
                XP, WP, HP, 0, nullptr, nullptr, nullptr);
            conv_wd <<<dim3(NB2 * KT2),     dim3(256), 0, stream>>>(e ? Wd_v : Wd_l, WP);
            down3_kernel<<<dim3(8 * NB2),   dim3(512), 0, stream>>>(HP, WP, oe);
        }
    }
}